// Round 1
// baseline (554.178 us; speedup 1.0000x reference)
//
#include <hip/hip_runtime.h>
#include <hip/hip_bf16.h>

// Problem constants (fixed by the reference):
// H=256, N0=150000, N1=80000, N2=20000, E1=300000.
// Layer 0 (GAT+SAGE over src0/dst0) is DEAD CODE in the reference -- its
// result is discarded. Only layer 1 contributes to the output.
// h = x @ W_gat is only ever read at rows < N1 (sources of src1 and
// self-loops of nodes < N1), so we compute just 80000 rows.

#define H 256
#define NS 80000   // rows of h we need (= n1)
#define ND 20000   // output nodes (= n2)

// ---------------------------------------------------------------------------
// Tiled f32 GEMM: C[M,256] = A[M,256] @ B[256,256] (+ bias) (+ C)
// BM=64, BN=64, BK=16; 256 threads; each thread computes 4x4.
// ---------------------------------------------------------------------------
template <bool ACC, bool BIAS>
__global__ __launch_bounds__(256) void gemm_f32(
    const float* __restrict__ A, const float* __restrict__ B,
    const float* __restrict__ bias, float* __restrict__ C, int M)
{
    __shared__ float As[16][68];  // transposed: As[k][m], pad to 68 (2-way max)
    __shared__ float Bs[16][68];

    const int tid  = threadIdx.x;
    const int row0 = blockIdx.x * 64;
    const int col0 = blockIdx.y * 64;
    const int tx = tid & 15;       // compute col group
    const int ty = tid >> 4;       // compute row group

    // load indexing
    const int lr  = tid >> 2;        // 0..63 : A row within tile
    const int lk  = (tid & 3) * 4;   // k quad for A
    const int bkr = tid >> 4;        // 0..15 : B k-row
    const int bc  = (tid & 15) * 4;  // B col quad

    float acc[4][4] = {};

    for (int k0 = 0; k0 < 256; k0 += 16) {
        const int ar = row0 + lr;
        float4 av;
        if (ar < M) av = *(const float4*)&A[(size_t)ar * 256 + k0 + lk];
        else        av = make_float4(0.f, 0.f, 0.f, 0.f);
        As[lk + 0][lr] = av.x;
        As[lk + 1][lr] = av.y;
        As[lk + 2][lr] = av.z;
        As[lk + 3][lr] = av.w;

        const float4 bv = *(const float4*)&B[(size_t)(k0 + bkr) * 256 + col0 + bc];
        *(float4*)&Bs[bkr][bc] = bv;
        __syncthreads();

#pragma unroll
        for (int k = 0; k < 16; ++k) {
            const float4 a = *(const float4*)&As[k][ty * 4];
            const float4 b = *(const float4*)&Bs[k][tx * 4];
            const float arr[4] = {a.x, a.y, a.z, a.w};
            const float brr[4] = {b.x, b.y, b.z, b.w};
#pragma unroll
            for (int i = 0; i < 4; ++i)
#pragma unroll
                for (int j = 0; j < 4; ++j)
                    acc[i][j] = fmaf(arr[i], brr[j], acc[i][j]);
        }
        __syncthreads();
    }

#pragma unroll
    for (int i = 0; i < 4; ++i) {
        const int row = row0 + ty * 4 + i;
        if (row >= M) continue;
        const int col = col0 + tx * 4;
        float4 v = make_float4(acc[i][0], acc[i][1], acc[i][2], acc[i][3]);
        if (BIAS) {
            const float4 bv = *(const float4*)&bias[col];
            v.x += bv.x; v.y += bv.y; v.z += bv.z; v.w += bv.w;
        }
        float* cp = &C[(size_t)row * 256 + col];
        if (ACC) {
            const float4 cv = *(const float4*)cp;
            v.x += cv.x; v.y += cv.y; v.z += cv.z; v.w += cv.w;
        }
        *(float4*)cp = v;
    }
}

// ---------------------------------------------------------------------------
// al_s[r] = dot(h[r], att_src); al_d[r] = dot(h[r], att_dst). 1 wave per row.
// ---------------------------------------------------------------------------
__global__ __launch_bounds__(256) void calc_al(
    const float* __restrict__ h, const float* __restrict__ asrc,
    const float* __restrict__ adst, float* __restrict__ al_s,
    float* __restrict__ al_d, int M)
{
    const int gw   = (blockIdx.x * 256 + threadIdx.x) >> 6;  // wave id = row
    const int lane = threadIdx.x & 63;
    if (gw >= M) return;
    const float4 hv = *(const float4*)&h[(size_t)gw * 256 + lane * 4];
    const float4 sv = *(const float4*)&asrc[lane * 4];
    const float4 dv = *(const float4*)&adst[lane * 4];
    float ps = hv.x * sv.x + hv.y * sv.y + hv.z * sv.z + hv.w * sv.w;
    float pd = hv.x * dv.x + hv.y * dv.y + hv.z * dv.z + hv.w * dv.w;
#pragma unroll
    for (int off = 32; off > 0; off >>= 1) {
        ps += __shfl_xor(ps, off);
        pd += __shfl_xor(pd, off);
    }
    if (lane == 0) { al_s[gw] = ps; al_d[gw] = pd; }
}

// ---------------------------------------------------------------------------
// CSR build over dst1
// ---------------------------------------------------------------------------
__global__ void edge_count(const int* __restrict__ dst, int* __restrict__ cnt, int E)
{
    const int i = blockIdx.x * 256 + threadIdx.x;
    if (i < E) atomicAdd(&cnt[dst[i]], 1);
}

__global__ __launch_bounds__(1024) void scan_excl(
    const int* __restrict__ cnt, int* __restrict__ ptr, int n)
{
    __shared__ int buf[1024];
    __shared__ int carry_s;
    const int tid = threadIdx.x;
    if (tid == 0) carry_s = 0;
    __syncthreads();
    for (int base = 0; base < n; base += 1024) {
        const int i = base + tid;
        const int v = (i < n) ? cnt[i] : 0;
        buf[tid] = v;
        __syncthreads();
        for (int off = 1; off < 1024; off <<= 1) {
            const int t = (tid >= off) ? buf[tid - off] : 0;
            __syncthreads();
            buf[tid] += t;
            __syncthreads();
        }
        const int carry = carry_s;
        if (i < n) ptr[i] = carry + buf[tid] - v;
        __syncthreads();
        if (tid == 0) carry_s = carry + buf[1023];
        __syncthreads();
    }
    if (tid == 0) ptr[n] = carry_s;
}

__global__ void edge_scatter(const int* __restrict__ dst, const int* __restrict__ ptr,
                             int* __restrict__ cursor, int* __restrict__ eidx, int E)
{
    const int i = blockIdx.x * 256 + threadIdx.x;
    if (i < E) {
        const int d = dst[i];
        const int pos = ptr[d] + atomicAdd(&cursor[d], 1);
        eidx[pos] = i;
    }
}

// ---------------------------------------------------------------------------
// GAT aggregation for dst nodes v in [0, ND).
// h1a[v] = sum_e coef_e * h[src_e] + coef_self * h[v] + b_gat
// ---------------------------------------------------------------------------
__device__ __forceinline__ float block_max(float v, float* red)
{
    const int tid = threadIdx.x;
    red[tid] = v;
    __syncthreads();
#pragma unroll
    for (int off = 128; off > 0; off >>= 1) {
        if (tid < off) red[tid] = fmaxf(red[tid], red[tid + off]);
        __syncthreads();
    }
    const float r = red[0];
    __syncthreads();
    return r;
}

__device__ __forceinline__ float block_sum(float v, float* red)
{
    const int tid = threadIdx.x;
    red[tid] = v;
    __syncthreads();
#pragma unroll
    for (int off = 128; off > 0; off >>= 1) {
        if (tid < off) red[tid] += red[tid + off];
        __syncthreads();
    }
    const float r = red[0];
    __syncthreads();
    return r;
}

__device__ __forceinline__ float lrelu02(float x) { return x > 0.f ? x : 0.2f * x; }

__global__ __launch_bounds__(256) void gat_aggr(
    const float* __restrict__ h, const float* __restrict__ al_s,
    const float* __restrict__ al_d, const int* __restrict__ src,
    const int* __restrict__ ptr, const int* __restrict__ eidx,
    const float* __restrict__ bg, float* __restrict__ h1a)
{
    __shared__ float red[256];
    const int v   = blockIdx.x;
    const int tid = threadIdx.x;
    const int p0 = ptr[v], p1 = ptr[v + 1];
    const float ad     = al_d[v];
    const float e_self = lrelu02(al_s[v] + ad);

    // pass 1: max
    float m = e_self;
    for (int p = p0 + tid; p < p1; p += 256) {
        const int s = src[eidx[p]];
        m = fmaxf(m, lrelu02(al_s[s] + ad));
    }
    m = block_max(m, red);

    // pass 2: sum of exp
    float zp = (tid == 0) ? __expf(e_self - m) : 0.f;
    for (int p = p0 + tid; p < p1; p += 256) {
        const int s = src[eidx[p]];
        zp += __expf(lrelu02(al_s[s] + ad) - m);
    }
    const float z = block_sum(zp, red);
    const float inv_z = 1.0f / z;

    // pass 3: per-channel accumulation (thread = channel)
    const int c = tid;
    float acc = __expf(e_self - m) * h[(size_t)v * 256 + c];
    for (int p = p0; p < p1; ++p) {
        const int s = src[eidx[p]];
        const float w = __expf(lrelu02(al_s[s] + ad) - m);
        acc = fmaf(w, h[(size_t)s * 256 + c], acc);
    }
    h1a[(size_t)v * 256 + c] = acc * inv_z + bg[c];
}

// ---------------------------------------------------------------------------
// SAGE mean aggregation. h1[s] for s>=ND is h[s] + bg (pure self-loop GAT).
// ---------------------------------------------------------------------------
__global__ __launch_bounds__(256) void sage_mean(
    const float* __restrict__ h, const float* __restrict__ h1a,
    const float* __restrict__ bg, const int* __restrict__ src,
    const int* __restrict__ ptr, const int* __restrict__ eidx,
    float* __restrict__ mean)
{
    const int v = blockIdx.x;
    const int c = threadIdx.x;
    const int p0 = ptr[v], p1 = ptr[v + 1];
    const float bgc = bg[c];
    float acc = 0.f;
    for (int p = p0; p < p1; ++p) {
        const int s = src[eidx[p]];
        acc += (s < ND) ? h1a[(size_t)s * 256 + c]
                        : (h[(size_t)s * 256 + c] + bgc);
    }
    const int n = p1 - p0;
    mean[(size_t)v * 256 + c] = (n > 0) ? acc / (float)n : 0.f;
}

// ---------------------------------------------------------------------------
// Row-normalize: out[v] = t[v] / max(||t[v]||, 1e-12)
// ---------------------------------------------------------------------------
__global__ __launch_bounds__(256) void rownorm(
    const float* __restrict__ t, float* __restrict__ out)
{
    __shared__ float red[256];
    const int v = blockIdx.x;
    const int c = threadIdx.x;
    const float x = t[(size_t)v * 256 + c];
    const float ss = block_sum(x * x, red);
    const float s = 1.0f / fmaxf(sqrtf(ss), 1e-12f);
    out[(size_t)v * 256 + c] = x * s;
}

// ---------------------------------------------------------------------------
extern "C" void kernel_launch(void* const* d_in, const int* in_sizes, int n_in,
                              void* d_out, int out_size, void* d_ws, size_t ws_size,
                              hipStream_t stream)
{
    const float* x    = (const float*)d_in[0];
    const float* Wg   = (const float*)d_in[1];
    const float* asrc = (const float*)d_in[2];
    const float* adst = (const float*)d_in[3];
    const float* bg   = (const float*)d_in[4];
    const float* Wl1  = (const float*)d_in[8];
    const float* bl1  = (const float*)d_in[9];
    const float* Wr1  = (const float*)d_in[10];
    const int*   src1 = (const int*)d_in[13];
    const int*   dst1 = (const int*)d_in[14];
    const int E1 = in_sizes[13];

    // workspace layout
    char* w = (char*)d_ws;
    float* h    = (float*)w;  w += (size_t)NS * 256 * 4;   // 81.92 MB
    float* h1a  = (float*)w;  w += (size_t)ND * 256 * 4;   // 20.48 MB
    float* tbuf = (float*)w;  w += (size_t)ND * 256 * 4;   // 20.48 MB
    float* mean = (float*)w;  w += (size_t)ND * 256 * 4;   // 20.48 MB
    float* al_s = (float*)w;  w += (size_t)NS * 4;
    float* al_d = (float*)w;  w += (size_t)NS * 4;
    int* cnt    = (int*)w;    w += (size_t)ND * 4;
    int* ptrv   = (int*)w;    w += (size_t)(ND + 4) * 4;
    int* cursor = (int*)w;    w += (size_t)ND * 4;
    int* eidx   = (int*)w;    w += (size_t)E1 * 4;

    const dim3 b256(256);

    // h = x @ W_gat  (rows < NS only)
    gemm_f32<false, false><<<dim3(NS / 64, 4), b256, 0, stream>>>(x, Wg, nullptr, h, NS);

    // attention logits
    calc_al<<<dim3(NS / 4), b256, 0, stream>>>(h, asrc, adst, al_s, al_d, NS);

    // CSR over dst1
    hipMemsetAsync(cnt, 0, (size_t)ND * 4, stream);
    hipMemsetAsync(cursor, 0, (size_t)ND * 4, stream);
    edge_count<<<dim3((E1 + 255) / 256), b256, 0, stream>>>(dst1, cnt, E1);
    scan_excl<<<dim3(1), dim3(1024), 0, stream>>>(cnt, ptrv, ND);
    edge_scatter<<<dim3((E1 + 255) / 256), b256, 0, stream>>>(dst1, ptrv, cursor, eidx, E1);

    // GAT aggregation for dst nodes < ND
    gat_aggr<<<dim3(ND), b256, 0, stream>>>(h, al_s, al_d, src1, ptrv, eidx, bg, h1a);

    // SAGE mean over same edges
    sage_mean<<<dim3(ND), b256, 0, stream>>>(h, h1a, bg, src1, ptrv, eidx, mean);

    // t = mean @ Wl1 + bl1 ; t += h1a @ Wr1
    const dim3 g2((ND + 63) / 64, 4);
    gemm_f32<false, true ><<<g2, b256, 0, stream>>>(mean, Wl1, bl1, tbuf, ND);
    gemm_f32<true,  false><<<g2, b256, 0, stream>>>(h1a, Wr1, nullptr, tbuf, ND);

    // normalize rows -> out
    rownorm<<<dim3(ND), b256, 0, stream>>>(tbuf, (float*)d_out);
}

// Round 2
// 333.939 us; speedup vs baseline: 1.6595x; 1.6595x over previous
//
#include <hip/hip_runtime.h>

// H=256, N1=80000, N2=20000, E1=300000. Layer 0 of the reference is dead code.
// Pipeline: h=x@Wg (bf16 MFMA, fused al_s/al_d epilogue) -> CSR(dst1) ->
// GAT softmax-aggregate -> SAGE mean -> fused [mean|h1a]@[Wl1;Wr1]+bias+rownorm.

#define NS 80000
#define ND 20000

typedef float   float4v  __attribute__((ext_vector_type(4)));
typedef float   f32x4    __attribute__((ext_vector_type(4)));
typedef __bf16  bf16x8   __attribute__((ext_vector_type(8)));
typedef unsigned short ushort8v __attribute__((ext_vector_type(8)));

union frag_u { ushort8v u; bf16x8 b; };

__device__ __forceinline__ float us2f(unsigned short u) {
    union { unsigned int i; float f; } x; x.i = ((unsigned)u) << 16; return x.f;
}
__device__ __forceinline__ unsigned short f2us(float f) {
    union { float f; unsigned int i; } x; x.f = f;
    unsigned int r = x.i + 0x7fffu + ((x.i >> 16) & 1u);   // RNE
    return (unsigned short)(r >> 16);
}
__device__ __forceinline__ float lrelu02(float x) { return x > 0.f ? x : 0.2f * x; }

// ---------------------------------------------------------------------------
// bf16 MFMA GEMM: C[M,256] = A[M,K] @ Bt[256,K]^T
// Block: 512 thr (8 waves, 2x4), tile 128x256, BK=32 (padded LDS stride 40).
// EPI=0: write bf16 h + fused al_s/al_d dot-products.
// EPI=1: +bias, row-L2-normalize, write f32 out (rows guarded by M).
// AF32:  A is f32, converted to bf16 during staging (x is read only once).
// ---------------------------------------------------------------------------
template <int EPI, bool AF32>
__global__ __launch_bounds__(512) void gemm_mfma(
    const void* __restrict__ Av, const unsigned short* __restrict__ Bt,
    int M, int K,
    unsigned short* __restrict__ hb_out,
    const float* __restrict__ avs, const float* __restrict__ avd,
    float* __restrict__ al_s, float* __restrict__ al_d,
    const float* __restrict__ bias, float* __restrict__ outp)
{
    __shared__ __align__(16) unsigned short Als[128][40];
    __shared__ __align__(16) unsigned short Bls[256][40];
    __shared__ float red0[128];
    __shared__ float red1[128];

    const int tid  = threadIdx.x;
    const int lane = tid & 63;
    const int wid  = tid >> 6;
    const int wr   = wid >> 2;      // 0..1
    const int wc   = wid & 3;       // 0..3
    const int row0 = blockIdx.x * 128;
    const int lg   = lane >> 4;     // 0..3
    const int lm   = lane & 15;

    f32x4 acc[4][4] = {};

    const int arow = tid >> 2;          // 0..127
    const int akof = (tid & 3) * 8;     // 0,8,16,24
    const int brow = tid >> 1;          // 0..255
    const int bkof = (tid & 1) * 16;    // 0,16

    for (int k0 = 0; k0 < K; k0 += 32) {
        // --- stage A tile (128 x 32) ---
        {
            const int grow = row0 + arow;
            ushort8v av;
            if constexpr (AF32) {
                const float* ag = (const float*)Av + (size_t)grow * K + k0 + akof;
                const float4v v0 = *(const float4v*)ag;
                const float4v v1 = *(const float4v*)(ag + 4);
                av[0]=f2us(v0[0]); av[1]=f2us(v0[1]); av[2]=f2us(v0[2]); av[3]=f2us(v0[3]);
                av[4]=f2us(v1[0]); av[5]=f2us(v1[1]); av[6]=f2us(v1[2]); av[7]=f2us(v1[3]);
            } else {
                if (grow < M) {
                    av = *(const ushort8v*)((const unsigned short*)Av + (size_t)grow * K + k0 + akof);
                } else {
                    av = (ushort8v){0,0,0,0,0,0,0,0};
                }
            }
            *(ushort8v*)&Als[arow][akof] = av;
        }
        // --- stage Bt tile (256 x 32) ---
        {
            const unsigned short* bg = Bt + (size_t)brow * K + k0 + bkof;
            *(ushort8v*)&Bls[brow][bkof]     = *(const ushort8v*)bg;
            *(ushort8v*)&Bls[brow][bkof + 8] = *(const ushort8v*)(bg + 8);
        }
        __syncthreads();

        frag_u af[4], bf[4];
#pragma unroll
        for (int m = 0; m < 4; ++m)
            af[m].u = *(const ushort8v*)&Als[wr*64 + m*16 + lm][lg*8];
#pragma unroll
        for (int n = 0; n < 4; ++n)
            bf[n].u = *(const ushort8v*)&Bls[wc*64 + n*16 + lm][lg*8];
#pragma unroll
        for (int m = 0; m < 4; ++m)
#pragma unroll
            for (int n = 0; n < 4; ++n)
                acc[m][n] = __builtin_amdgcn_mfma_f32_16x16x32_bf16(
                    af[m].b, bf[n].b, acc[m][n], 0, 0, 0);
        __syncthreads();
    }

    if constexpr (EPI == 0) {
        if (tid < 128) { red0[tid] = 0.f; red1[tid] = 0.f; }
        __syncthreads();
        float asv[4], adv[4];
#pragma unroll
        for (int n = 0; n < 4; ++n) {
            const int col = wc*64 + n*16 + lm;
            asv[n] = avs[col]; adv[n] = avd[col];
        }
#pragma unroll
        for (int m = 0; m < 4; ++m) {
#pragma unroll
            for (int j = 0; j < 4; ++j) {
                const int lr = wr*64 + m*16 + lg*4 + j;
                float ps = 0.f, pd = 0.f;
#pragma unroll
                for (int n = 0; n < 4; ++n) {
                    const int col = wc*64 + n*16 + lm;
                    const float v = acc[m][n][j];
                    ps += v * asv[n]; pd += v * adv[n];
                    hb_out[(size_t)(row0 + lr) * 256 + col] = f2us(v);
                }
#pragma unroll
                for (int off = 1; off < 16; off <<= 1) {
                    ps += __shfl_xor(ps, off);
                    pd += __shfl_xor(pd, off);
                }
                if (lm == 0) { atomicAdd(&red0[lr], ps); atomicAdd(&red1[lr], pd); }
            }
        }
        __syncthreads();
        if (tid < 128) { al_s[row0 + tid] = red0[tid]; al_d[row0 + tid] = red1[tid]; }
    } else {
        if (tid < 128) red0[tid] = 0.f;
        __syncthreads();
        float bv[4];
#pragma unroll
        for (int n = 0; n < 4; ++n) bv[n] = bias[wc*64 + n*16 + lm];
#pragma unroll
        for (int m = 0; m < 4; ++m) {
#pragma unroll
            for (int j = 0; j < 4; ++j) {
                const int lr = wr*64 + m*16 + lg*4 + j;
                float ss = 0.f;
#pragma unroll
                for (int n = 0; n < 4; ++n) {
                    const float v = acc[m][n][j] + bv[n];
                    acc[m][n][j] = v;
                    ss += v * v;
                }
#pragma unroll
                for (int off = 1; off < 16; off <<= 1) ss += __shfl_xor(ss, off);
                if (lm == 0) atomicAdd(&red0[lr], ss);
            }
        }
        __syncthreads();
#pragma unroll
        for (int m = 0; m < 4; ++m) {
#pragma unroll
            for (int j = 0; j < 4; ++j) {
                const int lr = wr*64 + m*16 + lg*4 + j;
                const int grow = row0 + lr;
                if (grow < M) {
                    const float inv = 1.0f / fmaxf(sqrtf(red0[lr]), 1e-12f);
#pragma unroll
                    for (int n = 0; n < 4; ++n)
                        outp[(size_t)grow * 256 + wc*64 + n*16 + lm] = acc[m][n][j] * inv;
                }
            }
        }
    }
}

// ---------------------------------------------------------------------------
// Weight prep: transpose + bf16-cast (tiny, latency-irrelevant).
// ---------------------------------------------------------------------------
__global__ __launch_bounds__(256) void prep_wg(const float* __restrict__ Wg,
                                               unsigned short* __restrict__ Wgt)
{
    const int n = blockIdx.x, k = threadIdx.x;
    Wgt[n * 256 + k] = f2us(Wg[k * 256 + n]);
}

__global__ __launch_bounds__(256) void prep_wcat(const float* __restrict__ Wl,
                                                 const float* __restrict__ Wr,
                                                 unsigned short* __restrict__ Wcat)
{
    const int n = blockIdx.x, k = threadIdx.x;
    Wcat[n * 512 + k]       = f2us(Wl[k * 256 + n]);
    Wcat[n * 512 + 256 + k] = f2us(Wr[k * 256 + n]);
}

// ---------------------------------------------------------------------------
// CSR build over dst1
// ---------------------------------------------------------------------------
__global__ void edge_count(const int* __restrict__ dst, int* __restrict__ cnt, int E)
{
    const int i = blockIdx.x * 256 + threadIdx.x;
    if (i < E) atomicAdd(&cnt[dst[i]], 1);
}

__global__ __launch_bounds__(1024) void scan_excl(
    const int* __restrict__ cnt, int* __restrict__ ptr, int n)
{
    __shared__ int part[1024];
    const int tid = threadIdx.x;
    const int chunk = (n + 1023) / 1024;
    const int i0 = tid * chunk;
    const int i1 = min(i0 + chunk, n);
    int s = 0;
    for (int i = i0; i < i1; ++i) s += cnt[i];
    part[tid] = s;
    __syncthreads();
    for (int off = 1; off < 1024; off <<= 1) {
        const int t = (tid >= off) ? part[tid - off] : 0;
        __syncthreads();
        part[tid] += t;
        __syncthreads();
    }
    int run = tid ? part[tid - 1] : 0;
    for (int i = i0; i < i1; ++i) { ptr[i] = run; run += cnt[i]; }
    if (tid == 1023) ptr[n] = part[1023];
}

__global__ void edge_scatter(const int* __restrict__ dst, const int* __restrict__ ptr,
                             int* __restrict__ cursor, int* __restrict__ eidx, int E)
{
    const int i = blockIdx.x * 256 + threadIdx.x;
    if (i < E) {
        const int d = dst[i];
        eidx[ptr[d] + atomicAdd(&cursor[d], 1)] = i;
    }
}

// ---------------------------------------------------------------------------
// block reductions
// ---------------------------------------------------------------------------
__device__ __forceinline__ float block_max(float v, float* red)
{
    const int tid = threadIdx.x;
    red[tid] = v; __syncthreads();
#pragma unroll
    for (int off = 128; off > 0; off >>= 1) {
        if (tid < off) red[tid] = fmaxf(red[tid], red[tid + off]);
        __syncthreads();
    }
    const float r = red[0]; __syncthreads();
    return r;
}
__device__ __forceinline__ float block_sum(float v, float* red)
{
    const int tid = threadIdx.x;
    red[tid] = v; __syncthreads();
#pragma unroll
    for (int off = 128; off > 0; off >>= 1) {
        if (tid < off) red[tid] += red[tid + off];
        __syncthreads();
    }
    const float r = red[0]; __syncthreads();
    return r;
}

// ---------------------------------------------------------------------------
// GAT softmax-aggregation for dst v<ND; writes h1a (bf16) into hcat[:,256:512].
// ---------------------------------------------------------------------------
__global__ __launch_bounds__(256) void gat_aggr(
    const unsigned short* __restrict__ hb, const float* __restrict__ al_s,
    const float* __restrict__ al_d, const int* __restrict__ src,
    const int* __restrict__ ptr, const int* __restrict__ eidx,
    const float* __restrict__ bg, unsigned short* __restrict__ hcat)
{
    __shared__ float red[256];
    const int v = blockIdx.x;
    const int tid = threadIdx.x;
    const int p0 = ptr[v], p1 = ptr[v + 1];
    const float adv = al_d[v];
    const float e_self = lrelu02(al_s[v] + adv);

    float m = e_self;
    for (int p = p0 + tid; p < p1; p += 256)
        m = fmaxf(m, lrelu02(al_s[src[eidx[p]]] + adv));
    m = block_max(m, red);

    float zp = (tid == 0) ? __expf(e_self - m) : 0.f;
    for (int p = p0 + tid; p < p1; p += 256)
        zp += __expf(lrelu02(al_s[src[eidx[p]]] + adv) - m);
    const float inv_z = 1.0f / block_sum(zp, red);

    const int c = tid;
    float acc = __expf(e_self - m) * us2f(hb[(size_t)v * 256 + c]);
    for (int p = p0; p < p1; ++p) {
        const int s = src[eidx[p]];
        const float w = __expf(lrelu02(al_s[s] + adv) - m);
        acc = fmaf(w, us2f(hb[(size_t)s * 256 + c]), acc);
    }
    hcat[(size_t)v * 512 + 256 + c] = f2us(acc * inv_z + bg[c]);
}

// ---------------------------------------------------------------------------
// SAGE mean; h1[s>=ND] = h[s]+bg (pure self-loop). Writes hcat[:,0:256].
// ---------------------------------------------------------------------------
__global__ __launch_bounds__(256) void sage_mean(
    const unsigned short* __restrict__ hb, const float* __restrict__ bg,
    const int* __restrict__ src, const int* __restrict__ ptr,
    const int* __restrict__ eidx, unsigned short* __restrict__ hcat)
{
    const int v = blockIdx.x;
    const int c = threadIdx.x;
    const int p0 = ptr[v], p1 = ptr[v + 1];
    const float bgc = bg[c];
    float acc = 0.f;
    for (int p = p0; p < p1; ++p) {
        const int s = src[eidx[p]];
        acc += (s < ND) ? us2f(hcat[(size_t)s * 512 + 256 + c])
                        : (us2f(hb[(size_t)s * 256 + c]) + bgc);
    }
    const int n = p1 - p0;
    hcat[(size_t)v * 512 + c] = f2us((n > 0) ? acc / (float)n : 0.f);
}

// ---------------------------------------------------------------------------
extern "C" void kernel_launch(void* const* d_in, const int* in_sizes, int n_in,
                              void* d_out, int out_size, void* d_ws, size_t ws_size,
                              hipStream_t stream)
{
    const float* x    = (const float*)d_in[0];
    const float* Wg   = (const float*)d_in[1];
    const float* asrc = (const float*)d_in[2];
    const float* adst = (const float*)d_in[3];
    const float* bg   = (const float*)d_in[4];
    const float* Wl1  = (const float*)d_in[8];
    const float* bl1  = (const float*)d_in[9];
    const float* Wr1  = (const float*)d_in[10];
    const int*   src1 = (const int*)d_in[13];
    const int*   dst1 = (const int*)d_in[14];
    const int E1 = in_sizes[13];

    // workspace
    char* w = (char*)d_ws;
    unsigned short* hb   = (unsigned short*)w; w += (size_t)NS * 256 * 2;   // 40.96 MB
    unsigned short* hcat = (unsigned short*)w; w += (size_t)ND * 512 * 2;   // 20.48 MB
    unsigned short* Wgt  = (unsigned short*)w; w += 256 * 256 * 2;
    unsigned short* Wcat = (unsigned short*)w; w += 256 * 512 * 2;
    float* al_s = (float*)w; w += (size_t)NS * 4;
    float* al_d = (float*)w; w += (size_t)NS * 4;
    int* cnt    = (int*)w;   w += (size_t)ND * 4;
    int* ptrv   = (int*)w;   w += (size_t)(ND + 4) * 4;
    int* cursor = (int*)w;   w += (size_t)ND * 4;
    int* eidx   = (int*)w;   w += (size_t)E1 * 4;

    const dim3 b256(256), b512(512);

    prep_wg  <<<dim3(256), b256, 0, stream>>>(Wg, Wgt);
    prep_wcat<<<dim3(256), b256, 0, stream>>>(Wl1, Wr1, Wcat);

    // h = x @ Wg (bf16) + fused al_s/al_d
    gemm_mfma<0, true><<<dim3(NS / 128), b512, 0, stream>>>(
        x, Wgt, NS, 256, hb, asrc, adst, al_s, al_d, nullptr, nullptr);

    // CSR over dst1
    hipMemsetAsync(cnt, 0, (size_t)ND * 4, stream);
    hipMemsetAsync(cursor, 0, (size_t)ND * 4, stream);
    edge_count  <<<dim3((E1 + 255) / 256), b256, 0, stream>>>(dst1, cnt, E1);
    scan_excl   <<<dim3(1), dim3(1024), 0, stream>>>(cnt, ptrv, ND);
    edge_scatter<<<dim3((E1 + 255) / 256), b256, 0, stream>>>(dst1, ptrv, cursor, eidx, E1);

    // GAT aggregate -> hcat[:,256:512]; SAGE mean -> hcat[:,0:256]
    gat_aggr <<<dim3(ND), b256, 0, stream>>>(hb, al_s, al_d, src1, ptrv, eidx, bg, hcat);
    sage_mean<<<dim3(ND), b256, 0, stream>>>(hb, bg, src1, ptrv, eidx, hcat);

    // out = normalize([mean|h1a] @ [Wl1;Wr1] + bl1)
    gemm_mfma<1, false><<<dim3((ND + 127) / 128), b512, 0, stream>>>(
        hcat, Wcat, ND, 512, nullptr, nullptr, nullptr, nullptr, nullptr,
        bl1, (float*)d_out);
}

// Round 3
// 214.734 us; speedup vs baseline: 2.5808x; 1.5551x over previous
//
#include <hip/hip_runtime.h>

// H=256, N1=80000, N2=20000, E1=300000. Layer 0 of the reference is dead code.
// Pipeline: h=x@Wg (bf16 MFMA, fused al_s/al_d epilogue) -> CSR(dst1, fused
// edge logits) -> GAT softmax-aggregate (slot-parallel) -> SAGE mean
// (slot-parallel) -> fused [mean|h1a]@[Wl1;Wr1]+bias+rownorm.

#define NS 80000
#define ND 20000

typedef float   float4v  __attribute__((ext_vector_type(4)));
typedef float   f32x4    __attribute__((ext_vector_type(4)));
typedef __bf16  bf16x8   __attribute__((ext_vector_type(8)));
typedef unsigned short ushort8v __attribute__((ext_vector_type(8)));

union frag_u { ushort8v u; bf16x8 b; };

__device__ __forceinline__ float us2f(unsigned short u) {
    union { unsigned int i; float f; } x; x.i = ((unsigned)u) << 16; return x.f;
}
__device__ __forceinline__ unsigned short f2us(float f) {
    union { float f; unsigned int i; } x; x.f = f;
    unsigned int r = x.i + 0x7fffu + ((x.i >> 16) & 1u);   // RNE
    return (unsigned short)(r >> 16);
}
__device__ __forceinline__ float lrelu02(float x) { return x > 0.f ? x : 0.2f * x; }

// ---------------------------------------------------------------------------
// bf16 MFMA GEMM: C[M,256] = A[M,K] @ Bt[256,K]^T
// Block: 512 thr (8 waves, 2x4), tile 128x256, BK=32 (padded LDS stride 40).
// EPI=0: write bf16 h + fused al_s/al_d dot-products.
// EPI=1: +bias, row-L2-normalize, write f32 out (rows guarded by M).
// AF32:  A is f32, converted to bf16 during staging (x is read only once).
// ---------------------------------------------------------------------------
template <int EPI, bool AF32>
__global__ __launch_bounds__(512) void gemm_mfma(
    const void* __restrict__ Av, const unsigned short* __restrict__ Bt,
    int M, int K,
    unsigned short* __restrict__ hb_out,
    const float* __restrict__ avs, const float* __restrict__ avd,
    float* __restrict__ al_s, float* __restrict__ al_d,
    const float* __restrict__ bias, float* __restrict__ outp)
{
    __shared__ __align__(16) unsigned short Als[128][40];
    __shared__ __align__(16) unsigned short Bls[256][40];
    __shared__ float red0[128];
    __shared__ float red1[128];

    const int tid  = threadIdx.x;
    const int lane = tid & 63;
    const int wid  = tid >> 6;
    const int wr   = wid >> 2;      // 0..1
    const int wc   = wid & 3;       // 0..3
    const int row0 = blockIdx.x * 128;
    const int lg   = lane >> 4;     // 0..3
    const int lm   = lane & 15;

    f32x4 acc[4][4] = {};

    const int arow = tid >> 2;          // 0..127
    const int akof = (tid & 3) * 8;     // 0,8,16,24
    const int brow = tid >> 1;          // 0..255
    const int bkof = (tid & 1) * 16;    // 0,16

    for (int k0 = 0; k0 < K; k0 += 32) {
        {
            const int grow = row0 + arow;
            ushort8v av;
            if constexpr (AF32) {
                const float* ag = (const float*)Av + (size_t)grow * K + k0 + akof;
                const float4v v0 = *(const float4v*)ag;
                const float4v v1 = *(const float4v*)(ag + 4);
                av[0]=f2us(v0[0]); av[1]=f2us(v0[1]); av[2]=f2us(v0[2]); av[3]=f2us(v0[3]);
                av[4]=f2us(v1[0]); av[5]=f2us(v1[1]); av[6]=f2us(v1[2]); av[7]=f2us(v1[3]);
            } else {
                if (grow < M) {
                    av = *(const ushort8v*)((const unsigned short*)Av + (size_t)grow * K + k0 + akof);
                } else {
                    av = (ushort8v){0,0,0,0,0,0,0,0};
                }
            }
            *(ushort8v*)&Als[arow][akof] = av;
        }
        {
            const unsigned short* bg = Bt + (size_t)brow * K + k0 + bkof;
            *(ushort8v*)&Bls[brow][bkof]     = *(const ushort8v*)bg;
            *(ushort8v*)&Bls[brow][bkof + 8] = *(const ushort8v*)(bg + 8);
        }
        __syncthreads();

        frag_u af[4], bf[4];
#pragma unroll
        for (int m = 0; m < 4; ++m)
            af[m].u = *(const ushort8v*)&Als[wr*64 + m*16 + lm][lg*8];
#pragma unroll
        for (int n = 0; n < 4; ++n)
            bf[n].u = *(const ushort8v*)&Bls[wc*64 + n*16 + lm][lg*8];
#pragma unroll
        for (int m = 0; m < 4; ++m)
#pragma unroll
            for (int n = 0; n < 4; ++n)
                acc[m][n] = __builtin_amdgcn_mfma_f32_16x16x32_bf16(
                    af[m].b, bf[n].b, acc[m][n], 0, 0, 0);
        __syncthreads();
    }

    if constexpr (EPI == 0) {
        if (tid < 128) { red0[tid] = 0.f; red1[tid] = 0.f; }
        __syncthreads();
        float asv[4], adv[4];
#pragma unroll
        for (int n = 0; n < 4; ++n) {
            const int col = wc*64 + n*16 + lm;
            asv[n] = avs[col]; adv[n] = avd[col];
        }
#pragma unroll
        for (int m = 0; m < 4; ++m) {
#pragma unroll
            for (int j = 0; j < 4; ++j) {
                const int lr = wr*64 + m*16 + lg*4 + j;
                float ps = 0.f, pd = 0.f;
#pragma unroll
                for (int n = 0; n < 4; ++n) {
                    const int col = wc*64 + n*16 + lm;
                    const float v = acc[m][n][j];
                    ps += v * asv[n]; pd += v * adv[n];
                    hb_out[(size_t)(row0 + lr) * 256 + col] = f2us(v);
                }
#pragma unroll
                for (int off = 1; off < 16; off <<= 1) {
                    ps += __shfl_xor(ps, off);
                    pd += __shfl_xor(pd, off);
                }
                if (lm == 0) { atomicAdd(&red0[lr], ps); atomicAdd(&red1[lr], pd); }
            }
        }
        __syncthreads();
        if (tid < 128) { al_s[row0 + tid] = red0[tid]; al_d[row0 + tid] = red1[tid]; }
    } else {
        if (tid < 128) red0[tid] = 0.f;
        __syncthreads();
        float bv[4];
#pragma unroll
        for (int n = 0; n < 4; ++n) bv[n] = bias[wc*64 + n*16 + lm];
#pragma unroll
        for (int m = 0; m < 4; ++m) {
#pragma unroll
            for (int j = 0; j < 4; ++j) {
                const int lr = wr*64 + m*16 + lg*4 + j;
                float ss = 0.f;
#pragma unroll
                for (int n = 0; n < 4; ++n) {
                    const float v = acc[m][n][j] + bv[n];
                    acc[m][n][j] = v;
                    ss += v * v;
                }
#pragma unroll
                for (int off = 1; off < 16; off <<= 1) ss += __shfl_xor(ss, off);
                if (lm == 0) atomicAdd(&red0[lr], ss);
            }
        }
        __syncthreads();
#pragma unroll
        for (int m = 0; m < 4; ++m) {
#pragma unroll
            for (int j = 0; j < 4; ++j) {
                const int lr = wr*64 + m*16 + lg*4 + j;
                const int grow = row0 + lr;
                if (grow < M) {
                    const float inv = 1.0f / fmaxf(sqrtf(red0[lr]), 1e-12f);
#pragma unroll
                    for (int n = 0; n < 4; ++n)
                        outp[(size_t)grow * 256 + wc*64 + n*16 + lm] = acc[m][n][j] * inv;
                }
            }
        }
    }
}

// ---------------------------------------------------------------------------
// Weight prep
// ---------------------------------------------------------------------------
__global__ __launch_bounds__(256) void prep_wg(const float* __restrict__ Wg,
                                               unsigned short* __restrict__ Wgt)
{
    const int n = blockIdx.x, k = threadIdx.x;
    Wgt[n * 256 + k] = f2us(Wg[k * 256 + n]);
}

__global__ __launch_bounds__(256) void prep_wcat(const float* __restrict__ Wl,
                                                 const float* __restrict__ Wr,
                                                 unsigned short* __restrict__ Wcat)
{
    const int n = blockIdx.x, k = threadIdx.x;
    Wcat[n * 512 + k]       = f2us(Wl[k * 256 + n]);
    Wcat[n * 512 + 256 + k] = f2us(Wr[k * 256 + n]);
}

// ---------------------------------------------------------------------------
// CSR build over dst1 (scatter fused with src + edge-logit precompute)
// ---------------------------------------------------------------------------
__global__ void edge_count(const int* __restrict__ dst, int* __restrict__ cnt, int E)
{
    const int i = blockIdx.x * 256 + threadIdx.x;
    if (i < E) atomicAdd(&cnt[dst[i]], 1);
}

__global__ __launch_bounds__(1024) void scan_excl(
    const int* __restrict__ cnt, int* __restrict__ ptr, int n)
{
    __shared__ int part[1024];
    const int tid = threadIdx.x;
    const int chunk = (n + 1023) / 1024;
    const int i0 = tid * chunk;
    const int i1 = min(i0 + chunk, n);
    int s = 0;
    for (int i = i0; i < i1; ++i) s += cnt[i];
    part[tid] = s;
    __syncthreads();
    for (int off = 1; off < 1024; off <<= 1) {
        const int t = (tid >= off) ? part[tid - off] : 0;
        __syncthreads();
        part[tid] += t;
        __syncthreads();
    }
    int run = tid ? part[tid - 1] : 0;
    for (int i = i0; i < i1; ++i) { ptr[i] = run; run += cnt[i]; }
    if (tid == 1023) ptr[n] = part[1023];
}

__global__ void edge_scatter(const int* __restrict__ src, const int* __restrict__ dst,
                             const int* __restrict__ ptr, int* __restrict__ cursor,
                             const float* __restrict__ al_s, const float* __restrict__ al_d,
                             int* __restrict__ ssort, float* __restrict__ elog, int E)
{
    const int i = blockIdx.x * 256 + threadIdx.x;
    if (i < E) {
        const int d = dst[i];
        const int s = src[i];
        const int pos = ptr[d] + atomicAdd(&cursor[d], 1);
        ssort[pos] = s;
        elog[pos] = lrelu02(al_s[s] + al_d[d]);
    }
}

// ---------------------------------------------------------------------------
// GAT aggregation, slot-parallel. Block=256: 8 slots x 32 lanes; lane holds
// 8 channels. Softmax stats computed redundantly per-thread (no barriers).
// Writes h1a (bf16) into hcat[:,256:512].
// ---------------------------------------------------------------------------
__global__ __launch_bounds__(256) void gat_aggr(
    const unsigned short* __restrict__ hb, const float* __restrict__ al_s,
    const float* __restrict__ al_d, const int* __restrict__ ssort,
    const float* __restrict__ elog, const int* __restrict__ ptr,
    const float* __restrict__ bg, unsigned short* __restrict__ hcat)
{
    __shared__ float lds[8][264];
    const int v    = blockIdx.x;
    const int tid  = threadIdx.x;
    const int slot = tid >> 5;
    const int l32  = tid & 31;
    const int c0   = l32 * 8;
    const int p0 = ptr[v], p1 = ptr[v + 1];

    const float e_self = lrelu02(al_s[v] + al_d[v]);
    float m = e_self;
    for (int p = p0; p < p1; ++p) m = fmaxf(m, elog[p]);
    float z = __expf(e_self - m);
    for (int p = p0; p < p1; ++p) z += __expf(elog[p] - m);
    const float inv_z = 1.0f / z;

    float acc[8];
    if (slot == 0) {
        const float ws = __expf(e_self - m);
        const ushort8v hv = *(const ushort8v*)&hb[(size_t)v * 256 + c0];
#pragma unroll
        for (int j = 0; j < 8; ++j) acc[j] = ws * us2f(hv[j]);
    } else {
#pragma unroll
        for (int j = 0; j < 8; ++j) acc[j] = 0.f;
    }
    for (int p = p0 + slot; p < p1; p += 8) {
        const int s = ssort[p];
        const float w = __expf(elog[p] - m);
        const ushort8v hv = *(const ushort8v*)&hb[(size_t)s * 256 + c0];
#pragma unroll
        for (int j = 0; j < 8; ++j) acc[j] = fmaf(w, us2f(hv[j]), acc[j]);
    }
    *(f32x4*)&lds[slot][c0]     = (f32x4){acc[0], acc[1], acc[2], acc[3]};
    *(f32x4*)&lds[slot][c0 + 4] = (f32x4){acc[4], acc[5], acc[6], acc[7]};
    __syncthreads();

    const int c = tid;
    float r = 0.f;
#pragma unroll
    for (int s2 = 0; s2 < 8; ++s2) r += lds[s2][c];
    hcat[(size_t)v * 512 + 256 + c] = f2us(r * inv_z + bg[c]);
}

// ---------------------------------------------------------------------------
// SAGE mean, slot-parallel. h1[s>=ND] = h[s]+bg handled as count*bg.
// Writes mean (bf16) into hcat[:,0:256].
// ---------------------------------------------------------------------------
__global__ __launch_bounds__(256) void sage_mean(
    const unsigned short* __restrict__ hb, const float* __restrict__ bg,
    const int* __restrict__ ssort, const int* __restrict__ ptr,
    unsigned short* __restrict__ hcat)
{
    __shared__ float lds[8][264];
    __shared__ int cnts[8];
    const int v    = blockIdx.x;
    const int tid  = threadIdx.x;
    const int slot = tid >> 5;
    const int l32  = tid & 31;
    const int c0   = l32 * 8;
    const int p0 = ptr[v], p1 = ptr[v + 1];

    float acc[8];
#pragma unroll
    for (int j = 0; j < 8; ++j) acc[j] = 0.f;
    int cge = 0;
    for (int p = p0 + slot; p < p1; p += 8) {
        const int s = ssort[p];
        const unsigned short* rp = (s < ND) ? &hcat[(size_t)s * 512 + 256 + c0]
                                            : &hb[(size_t)s * 256 + c0];
        cge += (s >= ND) ? 1 : 0;
        const ushort8v hv = *(const ushort8v*)rp;
#pragma unroll
        for (int j = 0; j < 8; ++j) acc[j] += us2f(hv[j]);
    }
    *(f32x4*)&lds[slot][c0]     = (f32x4){acc[0], acc[1], acc[2], acc[3]};
    *(f32x4*)&lds[slot][c0 + 4] = (f32x4){acc[4], acc[5], acc[6], acc[7]};
    if (l32 == 0) cnts[slot] = cge;
    __syncthreads();

    const int c = tid;
    float r = 0.f;
#pragma unroll
    for (int s2 = 0; s2 < 8; ++s2) r += lds[s2][c];
    int ng = 0;
#pragma unroll
    for (int s2 = 0; s2 < 8; ++s2) ng += cnts[s2];
    const int deg = p1 - p0;
    const float mean = (deg > 0) ? (r + (float)ng * bg[c]) / (float)deg : 0.f;
    hcat[(size_t)v * 512 + c] = f2us(mean);
}

// ---------------------------------------------------------------------------
extern "C" void kernel_launch(void* const* d_in, const int* in_sizes, int n_in,
                              void* d_out, int out_size, void* d_ws, size_t ws_size,
                              hipStream_t stream)
{
    const float* x    = (const float*)d_in[0];
    const float* Wg   = (const float*)d_in[1];
    const float* asrc = (const float*)d_in[2];
    const float* adst = (const float*)d_in[3];
    const float* bg   = (const float*)d_in[4];
    const float* Wl1  = (const float*)d_in[8];
    const float* bl1  = (const float*)d_in[9];
    const float* Wr1  = (const float*)d_in[10];
    const int*   src1 = (const int*)d_in[13];
    const int*   dst1 = (const int*)d_in[14];
    const int E1 = in_sizes[13];

    // workspace
    char* w = (char*)d_ws;
    unsigned short* hb   = (unsigned short*)w; w += (size_t)NS * 256 * 2;   // 40.96 MB
    unsigned short* hcat = (unsigned short*)w; w += (size_t)ND * 512 * 2;   // 20.48 MB
    unsigned short* Wgt  = (unsigned short*)w; w += 256 * 256 * 2;
    unsigned short* Wcat = (unsigned short*)w; w += 256 * 512 * 2;
    float* al_s = (float*)w; w += (size_t)NS * 4;
    float* al_d = (float*)w; w += (size_t)NS * 4;
    int* cnt    = (int*)w;   w += (size_t)ND * 4;
    int* ptrv   = (int*)w;   w += (size_t)(ND + 4) * 4;
    int* cursor = (int*)w;   w += (size_t)ND * 4;
    int* ssort  = (int*)w;   w += (size_t)E1 * 4;
    float* elog = (float*)w; w += (size_t)E1 * 4;

    const dim3 b256(256), b512(512);

    prep_wg  <<<dim3(256), b256, 0, stream>>>(Wg, Wgt);
    prep_wcat<<<dim3(256), b256, 0, stream>>>(Wl1, Wr1, Wcat);

    // h = x @ Wg (bf16) + fused al_s/al_d
    gemm_mfma<0, true><<<dim3(NS / 128), b512, 0, stream>>>(
        x, Wgt, NS, 256, hb, asrc, adst, al_s, al_d, nullptr, nullptr);

    // CSR over dst1 with fused edge logits
    hipMemsetAsync(cnt, 0, (size_t)ND * 4, stream);
    hipMemsetAsync(cursor, 0, (size_t)ND * 4, stream);
    edge_count  <<<dim3((E1 + 255) / 256), b256, 0, stream>>>(dst1, cnt, E1);
    scan_excl   <<<dim3(1), dim3(1024), 0, stream>>>(cnt, ptrv, ND);
    edge_scatter<<<dim3((E1 + 255) / 256), b256, 0, stream>>>(
        src1, dst1, ptrv, cursor, al_s, al_d, ssort, elog, E1);

    // GAT aggregate -> hcat[:,256:512]; SAGE mean -> hcat[:,0:256]
    gat_aggr <<<dim3(ND), b256, 0, stream>>>(hb, al_s, al_d, ssort, elog, ptrv, bg, hcat);
    sage_mean<<<dim3(ND), b256, 0, stream>>>(hb, bg, ssort, ptrv, hcat);

    // out = normalize([mean|h1a] @ [Wl1;Wr1] + bl1)
    gemm_mfma<1, false><<<dim3((ND + 127) / 128), b512, 0, stream>>>(
        hcat, Wcat, ND, 512, nullptr, nullptr, nullptr, nullptr, nullptr,
        bl1, (float*)d_out);
}

// Round 4
// 213.633 us; speedup vs baseline: 2.5941x; 1.0052x over previous
//
#include <hip/hip_runtime.h>

// H=256, N1=80000, N2=20000, E1=300000. Layer 0 of the reference is dead code.
// Pipeline: h=x@Wg (bf16 MFMA, fused al_s/al_d epilogue) -> CSR(dst1, fused
// edge logits) -> GAT softmax-aggregate (slot-parallel) -> SAGE mean
// (slot-parallel) -> fused [mean|h1a]@[Wl1;Wr1]+bias+rownorm.
// R4: replaced hipMemsetAsync (90us pathological fillBuffer in graph replay)
// with a custom zero kernel over the adjacent cnt+cursor region.

#define NS 80000
#define ND 20000

typedef float   float4v  __attribute__((ext_vector_type(4)));
typedef float   f32x4    __attribute__((ext_vector_type(4)));
typedef __bf16  bf16x8   __attribute__((ext_vector_type(8)));
typedef unsigned short ushort8v __attribute__((ext_vector_type(8)));
typedef int     int4v    __attribute__((ext_vector_type(4)));

union frag_u { ushort8v u; bf16x8 b; };

__device__ __forceinline__ float us2f(unsigned short u) {
    union { unsigned int i; float f; } x; x.i = ((unsigned)u) << 16; return x.f;
}
__device__ __forceinline__ unsigned short f2us(float f) {
    union { float f; unsigned int i; } x; x.f = f;
    unsigned int r = x.i + 0x7fffu + ((x.i >> 16) & 1u);   // RNE
    return (unsigned short)(r >> 16);
}
__device__ __forceinline__ float lrelu02(float x) { return x > 0.f ? x : 0.2f * x; }

// ---------------------------------------------------------------------------
// zero an int region (replaces hipMemsetAsync)
// ---------------------------------------------------------------------------
__global__ __launch_bounds__(256) void zero_i32(int* __restrict__ p, int n4)
{
    const int i = blockIdx.x * 256 + threadIdx.x;
    if (i < n4) ((int4v*)p)[i] = (int4v){0, 0, 0, 0};
}

// ---------------------------------------------------------------------------
// bf16 MFMA GEMM: C[M,256] = A[M,K] @ Bt[256,K]^T
// Block: 512 thr (8 waves, 2x4), tile 128x256, BK=32 (padded LDS stride 40).
// EPI=0: write bf16 h + fused al_s/al_d dot-products.
// EPI=1: +bias, row-L2-normalize, write f32 out (rows guarded by M).
// AF32:  A is f32, converted to bf16 during staging (x is read only once).
// ---------------------------------------------------------------------------
template <int EPI, bool AF32>
__global__ __launch_bounds__(512) void gemm_mfma(
    const void* __restrict__ Av, const unsigned short* __restrict__ Bt,
    int M, int K,
    unsigned short* __restrict__ hb_out,
    const float* __restrict__ avs, const float* __restrict__ avd,
    float* __restrict__ al_s, float* __restrict__ al_d,
    const float* __restrict__ bias, float* __restrict__ outp)
{
    __shared__ __align__(16) unsigned short Als[128][40];
    __shared__ __align__(16) unsigned short Bls[256][40];
    __shared__ float red0[128];
    __shared__ float red1[128];

    const int tid  = threadIdx.x;
    const int lane = tid & 63;
    const int wid  = tid >> 6;
    const int wr   = wid >> 2;      // 0..1
    const int wc   = wid & 3;       // 0..3
    const int row0 = blockIdx.x * 128;
    const int lg   = lane >> 4;     // 0..3
    const int lm   = lane & 15;

    f32x4 acc[4][4] = {};

    const int arow = tid >> 2;          // 0..127
    const int akof = (tid & 3) * 8;     // 0,8,16,24
    const int brow = tid >> 1;          // 0..255
    const int bkof = (tid & 1) * 16;    // 0,16

    for (int k0 = 0; k0 < K; k0 += 32) {
        {
            const int grow = row0 + arow;
            ushort8v av;
            if constexpr (AF32) {
                const float* ag = (const float*)Av + (size_t)grow * K + k0 + akof;
                const float4v v0 = *(const float4v*)ag;
                const float4v v1 = *(const float4v*)(ag + 4);
                av[0]=f2us(v0[0]); av[1]=f2us(v0[1]); av[2]=f2us(v0[2]); av[3]=f2us(v0[3]);
                av[4]=f2us(v1[0]); av[5]=f2us(v1[1]); av[6]=f2us(v1[2]); av[7]=f2us(v1[3]);
            } else {
                if (grow < M) {
                    av = *(const ushort8v*)((const unsigned short*)Av + (size_t)grow * K + k0 + akof);
                } else {
                    av = (ushort8v){0,0,0,0,0,0,0,0};
                }
            }
            *(ushort8v*)&Als[arow][akof] = av;
        }
        {
            const unsigned short* bg = Bt + (size_t)brow * K + k0 + bkof;
            *(ushort8v*)&Bls[brow][bkof]     = *(const ushort8v*)bg;
            *(ushort8v*)&Bls[brow][bkof + 8] = *(const ushort8v*)(bg + 8);
        }
        __syncthreads();

        frag_u af[4], bf[4];
#pragma unroll
        for (int m = 0; m < 4; ++m)
            af[m].u = *(const ushort8v*)&Als[wr*64 + m*16 + lm][lg*8];
#pragma unroll
        for (int n = 0; n < 4; ++n)
            bf[n].u = *(const ushort8v*)&Bls[wc*64 + n*16 + lm][lg*8];
#pragma unroll
        for (int m = 0; m < 4; ++m)
#pragma unroll
            for (int n = 0; n < 4; ++n)
                acc[m][n] = __builtin_amdgcn_mfma_f32_16x16x32_bf16(
                    af[m].b, bf[n].b, acc[m][n], 0, 0, 0);
        __syncthreads();
    }

    if constexpr (EPI == 0) {
        if (tid < 128) { red0[tid] = 0.f; red1[tid] = 0.f; }
        __syncthreads();
        float asv[4], adv[4];
#pragma unroll
        for (int n = 0; n < 4; ++n) {
            const int col = wc*64 + n*16 + lm;
            asv[n] = avs[col]; adv[n] = avd[col];
        }
#pragma unroll
        for (int m = 0; m < 4; ++m) {
#pragma unroll
            for (int j = 0; j < 4; ++j) {
                const int lr = wr*64 + m*16 + lg*4 + j;
                float ps = 0.f, pd = 0.f;
#pragma unroll
                for (int n = 0; n < 4; ++n) {
                    const int col = wc*64 + n*16 + lm;
                    const float v = acc[m][n][j];
                    ps += v * asv[n]; pd += v * adv[n];
                    hb_out[(size_t)(row0 + lr) * 256 + col] = f2us(v);
                }
#pragma unroll
                for (int off = 1; off < 16; off <<= 1) {
                    ps += __shfl_xor(ps, off);
                    pd += __shfl_xor(pd, off);
                }
                if (lm == 0) { atomicAdd(&red0[lr], ps); atomicAdd(&red1[lr], pd); }
            }
        }
        __syncthreads();
        if (tid < 128) { al_s[row0 + tid] = red0[tid]; al_d[row0 + tid] = red1[tid]; }
    } else {
        if (tid < 128) red0[tid] = 0.f;
        __syncthreads();
        float bv[4];
#pragma unroll
        for (int n = 0; n < 4; ++n) bv[n] = bias[wc*64 + n*16 + lm];
#pragma unroll
        for (int m = 0; m < 4; ++m) {
#pragma unroll
            for (int j = 0; j < 4; ++j) {
                const int lr = wr*64 + m*16 + lg*4 + j;
                float ss = 0.f;
#pragma unroll
                for (int n = 0; n < 4; ++n) {
                    const float v = acc[m][n][j] + bv[n];
                    acc[m][n][j] = v;
                    ss += v * v;
                }
#pragma unroll
                for (int off = 1; off < 16; off <<= 1) ss += __shfl_xor(ss, off);
                if (lm == 0) atomicAdd(&red0[lr], ss);
            }
        }
        __syncthreads();
#pragma unroll
        for (int m = 0; m < 4; ++m) {
#pragma unroll
            for (int j = 0; j < 4; ++j) {
                const int lr = wr*64 + m*16 + lg*4 + j;
                const int grow = row0 + lr;
                if (grow < M) {
                    const float inv = 1.0f / fmaxf(sqrtf(red0[lr]), 1e-12f);
#pragma unroll
                    for (int n = 0; n < 4; ++n)
                        outp[(size_t)grow * 256 + wc*64 + n*16 + lm] = acc[m][n][j] * inv;
                }
            }
        }
    }
}

// ---------------------------------------------------------------------------
// Weight prep
// ---------------------------------------------------------------------------
__global__ __launch_bounds__(256) void prep_wg(const float* __restrict__ Wg,
                                               unsigned short* __restrict__ Wgt)
{
    const int n = blockIdx.x, k = threadIdx.x;
    Wgt[n * 256 + k] = f2us(Wg[k * 256 + n]);
}

__global__ __launch_bounds__(256) void prep_wcat(const float* __restrict__ Wl,
                                                 const float* __restrict__ Wr,
                                                 unsigned short* __restrict__ Wcat)
{
    const int n = blockIdx.x, k = threadIdx.x;
    Wcat[n * 512 + k]       = f2us(Wl[k * 256 + n]);
    Wcat[n * 512 + 256 + k] = f2us(Wr[k * 256 + n]);
}

// ---------------------------------------------------------------------------
// CSR build over dst1 (scatter fused with src + edge-logit precompute)
// ---------------------------------------------------------------------------
__global__ void edge_count(const int* __restrict__ dst, int* __restrict__ cnt, int E)
{
    const int i = blockIdx.x * 256 + threadIdx.x;
    if (i < E) atomicAdd(&cnt[dst[i]], 1);
}

__global__ __launch_bounds__(1024) void scan_excl(
    const int* __restrict__ cnt, int* __restrict__ ptr, int n)
{
    __shared__ int part[1024];
    const int tid = threadIdx.x;
    const int chunk = (n + 1023) / 1024;
    const int i0 = tid * chunk;
    const int i1 = min(i0 + chunk, n);
    int s = 0;
    for (int i = i0; i < i1; ++i) s += cnt[i];
    part[tid] = s;
    __syncthreads();
    for (int off = 1; off < 1024; off <<= 1) {
        const int t = (tid >= off) ? part[tid - off] : 0;
        __syncthreads();
        part[tid] += t;
        __syncthreads();
    }
    int run = tid ? part[tid - 1] : 0;
    for (int i = i0; i < i1; ++i) { ptr[i] = run; run += cnt[i]; }
    if (tid == 1023) ptr[n] = part[1023];
}

__global__ void edge_scatter(const int* __restrict__ src, const int* __restrict__ dst,
                             const int* __restrict__ ptr, int* __restrict__ cursor,
                             const float* __restrict__ al_s, const float* __restrict__ al_d,
                             int* __restrict__ ssort, float* __restrict__ elog, int E)
{
    const int i = blockIdx.x * 256 + threadIdx.x;
    if (i < E) {
        const int d = dst[i];
        const int s = src[i];
        const int pos = ptr[d] + atomicAdd(&cursor[d], 1);
        ssort[pos] = s;
        elog[pos] = lrelu02(al_s[s] + al_d[d]);
    }
}

// ---------------------------------------------------------------------------
// GAT aggregation, slot-parallel. Block=256: 8 slots x 32 lanes; lane holds
// 8 channels. Softmax stats computed redundantly per-thread (no barriers).
// Writes h1a (bf16) into hcat[:,256:512].
// ---------------------------------------------------------------------------
__global__ __launch_bounds__(256) void gat_aggr(
    const unsigned short* __restrict__ hb, const float* __restrict__ al_s,
    const float* __restrict__ al_d, const int* __restrict__ ssort,
    const float* __restrict__ elog, const int* __restrict__ ptr,
    const float* __restrict__ bg, unsigned short* __restrict__ hcat)
{
    __shared__ float lds[8][264];
    const int v    = blockIdx.x;
    const int tid  = threadIdx.x;
    const int slot = tid >> 5;
    const int l32  = tid & 31;
    const int c0   = l32 * 8;
    const int p0 = ptr[v], p1 = ptr[v + 1];

    const float e_self = lrelu02(al_s[v] + al_d[v]);
    float m = e_self;
    for (int p = p0; p < p1; ++p) m = fmaxf(m, elog[p]);
    float z = __expf(e_self - m);
    for (int p = p0; p < p1; ++p) z += __expf(elog[p] - m);
    const float inv_z = 1.0f / z;

    float acc[8];
    if (slot == 0) {
        const float ws = __expf(e_self - m);
        const ushort8v hv = *(const ushort8v*)&hb[(size_t)v * 256 + c0];
#pragma unroll
        for (int j = 0; j < 8; ++j) acc[j] = ws * us2f(hv[j]);
    } else {
#pragma unroll
        for (int j = 0; j < 8; ++j) acc[j] = 0.f;
    }
    for (int p = p0 + slot; p < p1; p += 8) {
        const int s = ssort[p];
        const float w = __expf(elog[p] - m);
        const ushort8v hv = *(const ushort8v*)&hb[(size_t)s * 256 + c0];
#pragma unroll
        for (int j = 0; j < 8; ++j) acc[j] = fmaf(w, us2f(hv[j]), acc[j]);
    }
    *(f32x4*)&lds[slot][c0]     = (f32x4){acc[0], acc[1], acc[2], acc[3]};
    *(f32x4*)&lds[slot][c0 + 4] = (f32x4){acc[4], acc[5], acc[6], acc[7]};
    __syncthreads();

    const int c = tid;
    float r = 0.f;
#pragma unroll
    for (int s2 = 0; s2 < 8; ++s2) r += lds[s2][c];
    hcat[(size_t)v * 512 + 256 + c] = f2us(r * inv_z + bg[c]);
}

// ---------------------------------------------------------------------------
// SAGE mean, slot-parallel. h1[s>=ND] = h[s]+bg handled as count*bg.
// Writes mean (bf16) into hcat[:,0:256].
// ---------------------------------------------------------------------------
__global__ __launch_bounds__(256) void sage_mean(
    const unsigned short* __restrict__ hb, const float* __restrict__ bg,
    const int* __restrict__ ssort, const int* __restrict__ ptr,
    unsigned short* __restrict__ hcat)
{
    __shared__ float lds[8][264];
    __shared__ int cnts[8];
    const int v    = blockIdx.x;
    const int tid  = threadIdx.x;
    const int slot = tid >> 5;
    const int l32  = tid & 31;
    const int c0   = l32 * 8;
    const int p0 = ptr[v], p1 = ptr[v + 1];

    float acc[8];
#pragma unroll
    for (int j = 0; j < 8; ++j) acc[j] = 0.f;
    int cge = 0;
    for (int p = p0 + slot; p < p1; p += 8) {
        const int s = ssort[p];
        const unsigned short* rp = (s < ND) ? &hcat[(size_t)s * 512 + 256 + c0]
                                            : &hb[(size_t)s * 256 + c0];
        cge += (s >= ND) ? 1 : 0;
        const ushort8v hv = *(const ushort8v*)rp;
#pragma unroll
        for (int j = 0; j < 8; ++j) acc[j] += us2f(hv[j]);
    }
    *(f32x4*)&lds[slot][c0]     = (f32x4){acc[0], acc[1], acc[2], acc[3]};
    *(f32x4*)&lds[slot][c0 + 4] = (f32x4){acc[4], acc[5], acc[6], acc[7]};
    if (l32 == 0) cnts[slot] = cge;
    __syncthreads();

    const int c = tid;
    float r = 0.f;
#pragma unroll
    for (int s2 = 0; s2 < 8; ++s2) r += lds[s2][c];
    int ng = 0;
#pragma unroll
    for (int s2 = 0; s2 < 8; ++s2) ng += cnts[s2];
    const int deg = p1 - p0;
    const float mean = (deg > 0) ? (r + (float)ng * bg[c]) / (float)deg : 0.f;
    hcat[(size_t)v * 512 + c] = f2us(mean);
}

// ---------------------------------------------------------------------------
extern "C" void kernel_launch(void* const* d_in, const int* in_sizes, int n_in,
                              void* d_out, int out_size, void* d_ws, size_t ws_size,
                              hipStream_t stream)
{
    const float* x    = (const float*)d_in[0];
    const float* Wg   = (const float*)d_in[1];
    const float* asrc = (const float*)d_in[2];
    const float* adst = (const float*)d_in[3];
    const float* bg   = (const float*)d_in[4];
    const float* Wl1  = (const float*)d_in[8];
    const float* bl1  = (const float*)d_in[9];
    const float* Wr1  = (const float*)d_in[10];
    const int*   src1 = (const int*)d_in[13];
    const int*   dst1 = (const int*)d_in[14];
    const int E1 = in_sizes[13];

    // workspace (cnt+cursor adjacent so one zero kernel covers both)
    char* w = (char*)d_ws;
    unsigned short* hb   = (unsigned short*)w; w += (size_t)NS * 256 * 2;   // 40.96 MB
    unsigned short* hcat = (unsigned short*)w; w += (size_t)ND * 512 * 2;   // 20.48 MB
    unsigned short* Wgt  = (unsigned short*)w; w += 256 * 256 * 2;
    unsigned short* Wcat = (unsigned short*)w; w += 256 * 512 * 2;
    float* al_s = (float*)w; w += (size_t)NS * 4;
    float* al_d = (float*)w; w += (size_t)NS * 4;
    int* cnt    = (int*)w;   w += (size_t)ND * 4;
    int* cursor = (int*)w;   w += (size_t)ND * 4;
    int* ptrv   = (int*)w;   w += (size_t)(ND + 4) * 4;
    int* ssort  = (int*)w;   w += (size_t)E1 * 4;
    float* elog = (float*)w; w += (size_t)E1 * 4;

    const dim3 b256(256), b512(512);

    // zero cnt+cursor (2*ND ints = 10000 int4s)
    zero_i32<<<dim3((2 * ND / 4 + 255) / 256), b256, 0, stream>>>(cnt, 2 * ND / 4);

    prep_wg  <<<dim3(256), b256, 0, stream>>>(Wg, Wgt);
    prep_wcat<<<dim3(256), b256, 0, stream>>>(Wl1, Wr1, Wcat);

    // h = x @ Wg (bf16) + fused al_s/al_d
    gemm_mfma<0, true><<<dim3(NS / 128), b512, 0, stream>>>(
        x, Wgt, NS, 256, hb, asrc, adst, al_s, al_d, nullptr, nullptr);

    // CSR over dst1 with fused edge logits
    edge_count  <<<dim3((E1 + 255) / 256), b256, 0, stream>>>(dst1, cnt, E1);
    scan_excl   <<<dim3(1), dim3(1024), 0, stream>>>(cnt, ptrv, ND);
    edge_scatter<<<dim3((E1 + 255) / 256), b256, 0, stream>>>(
        src1, dst1, ptrv, cursor, al_s, al_d, ssort, elog, E1);

    // GAT aggregate -> hcat[:,256:512]; SAGE mean -> hcat[:,0:256]
    gat_aggr <<<dim3(ND), b256, 0, stream>>>(hb, al_s, al_d, ssort, elog, ptrv, bg, hcat);
    sage_mean<<<dim3(ND), b256, 0, stream>>>(hb, bg, ssort, ptrv, hcat);

    // out = normalize([mean|h1a] @ [Wl1;Wr1] + bl1)
    gemm_mfma<1, false><<<dim3((ND + 127) / 128), b512, 0, stream>>>(
        hcat, Wcat, ND, 512, nullptr, nullptr, nullptr, nullptr, nullptr,
        bl1, (float*)d_out);
}

// Round 5
// 201.775 us; speedup vs baseline: 2.7465x; 1.0588x over previous
//
#include <hip/hip_runtime.h>

// H=256, N1=80000, N2=20000, E1=300000. Layer 0 of the reference is dead code.
// Pipeline: prep (zero + weight transpose/cast) -> h=x@Wg+bg (bf16 MFMA,
// fused al_s/al_d epilogue, pre-bias) -> CSR(dst1, fused edge logits) ->
// fused GAT-softmax-aggregate + SAGE partial-sum (s>=ND) -> SAGE finisher
// (s<ND h1a gathers) -> fused [mean|h1a]@[Wl1;Wr1]+bias+rownorm.
// bg folding: softmax coefs sum to 1, so aggregating (h+bg) gives gat+bg
// directly, and sage's s>=ND term needs h+bg anyway.

#define NS 80000
#define ND 20000

typedef float   float4v  __attribute__((ext_vector_type(4)));
typedef float   f32x4    __attribute__((ext_vector_type(4)));
typedef __bf16  bf16x8   __attribute__((ext_vector_type(8)));
typedef unsigned short ushort8v __attribute__((ext_vector_type(8)));
typedef int     int4v    __attribute__((ext_vector_type(4)));

union frag_u { ushort8v u; bf16x8 b; };

__device__ __forceinline__ float us2f(unsigned short u) {
    union { unsigned int i; float f; } x; x.i = ((unsigned)u) << 16; return x.f;
}
__device__ __forceinline__ unsigned short f2us(float f) {
    union { float f; unsigned int i; } x; x.f = f;
    unsigned int r = x.i + 0x7fffu + ((x.i >> 16) & 1u);   // RNE
    return (unsigned short)(r >> 16);
}
__device__ __forceinline__ float lrelu02(float x) { return x > 0.f ? x : 0.2f * x; }

// ---------------------------------------------------------------------------
// prep: blocks 0..255 -> Wgt; 256..511 -> Wcat; 512.. -> zero cnt+cursor
// ---------------------------------------------------------------------------
__global__ __launch_bounds__(256) void prep_misc(
    const float* __restrict__ Wg, const float* __restrict__ Wl,
    const float* __restrict__ Wr, unsigned short* __restrict__ Wgt,
    unsigned short* __restrict__ Wcat, int* __restrict__ zerop, int nz4)
{
    const int b = blockIdx.x, t = threadIdx.x;
    if (b < 256) {
        Wgt[b * 256 + t] = f2us(Wg[t * 256 + b]);
    } else if (b < 512) {
        const int n = b - 256;
        Wcat[n * 512 + t]       = f2us(Wl[t * 256 + n]);
        Wcat[n * 512 + 256 + t] = f2us(Wr[t * 256 + n]);
    } else {
        const int i = (b - 512) * 256 + t;
        if (i < nz4) ((int4v*)zerop)[i] = (int4v){0, 0, 0, 0};
    }
}

// ---------------------------------------------------------------------------
// bf16 MFMA GEMM: C[M,256] = A[M,K] @ Bt[256,K]^T
// Block: 512 thr (8 waves, 2x4), tile 128x256, BK=32 (padded LDS stride 40).
// EPI=0: write bf16 (h+bg) + fused al_s/al_d dot-products (pre-bias).
// EPI=1: +bias, row-L2-normalize, write f32 out (rows guarded by M).
// AF32:  A is f32, converted to bf16 during staging (x is read only once).
// ---------------------------------------------------------------------------
template <int EPI, bool AF32>
__global__ __launch_bounds__(512) void gemm_mfma(
    const void* __restrict__ Av, const unsigned short* __restrict__ Bt,
    int M, int K,
    unsigned short* __restrict__ hb_out,
    const float* __restrict__ avs, const float* __restrict__ avd,
    float* __restrict__ al_s, float* __restrict__ al_d,
    const float* __restrict__ bias, float* __restrict__ outp)
{
    __shared__ __align__(16) unsigned short Als[128][40];
    __shared__ __align__(16) unsigned short Bls[256][40];
    __shared__ float red0[128];
    __shared__ float red1[128];

    const int tid  = threadIdx.x;
    const int lane = tid & 63;
    const int wid  = tid >> 6;
    const int wr   = wid >> 2;      // 0..1
    const int wc   = wid & 3;       // 0..3
    const int row0 = blockIdx.x * 128;
    const int lg   = lane >> 4;     // 0..3
    const int lm   = lane & 15;

    f32x4 acc[4][4] = {};

    const int arow = tid >> 2;          // 0..127
    const int akof = (tid & 3) * 8;     // 0,8,16,24
    const int brow = tid >> 1;          // 0..255
    const int bkof = (tid & 1) * 16;    // 0,16

    for (int k0 = 0; k0 < K; k0 += 32) {
        {
            const int grow = row0 + arow;
            ushort8v av;
            if constexpr (AF32) {
                const float* ag = (const float*)Av + (size_t)grow * K + k0 + akof;
                const float4v v0 = *(const float4v*)ag;
                const float4v v1 = *(const float4v*)(ag + 4);
                av[0]=f2us(v0[0]); av[1]=f2us(v0[1]); av[2]=f2us(v0[2]); av[3]=f2us(v0[3]);
                av[4]=f2us(v1[0]); av[5]=f2us(v1[1]); av[6]=f2us(v1[2]); av[7]=f2us(v1[3]);
            } else {
                if (grow < M) {
                    av = *(const ushort8v*)((const unsigned short*)Av + (size_t)grow * K + k0 + akof);
                } else {
                    av = (ushort8v){0,0,0,0,0,0,0,0};
                }
            }
            *(ushort8v*)&Als[arow][akof] = av;
        }
        {
            const unsigned short* bg = Bt + (size_t)brow * K + k0 + bkof;
            *(ushort8v*)&Bls[brow][bkof]     = *(const ushort8v*)bg;
            *(ushort8v*)&Bls[brow][bkof + 8] = *(const ushort8v*)(bg + 8);
        }
        __syncthreads();

        frag_u af[4], bf[4];
#pragma unroll
        for (int m = 0; m < 4; ++m)
            af[m].u = *(const ushort8v*)&Als[wr*64 + m*16 + lm][lg*8];
#pragma unroll
        for (int n = 0; n < 4; ++n)
            bf[n].u = *(const ushort8v*)&Bls[wc*64 + n*16 + lm][lg*8];
#pragma unroll
        for (int m = 0; m < 4; ++m)
#pragma unroll
            for (int n = 0; n < 4; ++n)
                acc[m][n] = __builtin_amdgcn_mfma_f32_16x16x32_bf16(
                    af[m].b, bf[n].b, acc[m][n], 0, 0, 0);
        __syncthreads();
    }

    if constexpr (EPI == 0) {
        if (tid < 128) { red0[tid] = 0.f; red1[tid] = 0.f; }
        __syncthreads();
        float asv[4], adv[4], bgv[4];
#pragma unroll
        for (int n = 0; n < 4; ++n) {
            const int col = wc*64 + n*16 + lm;
            asv[n] = avs[col]; adv[n] = avd[col]; bgv[n] = bias[col];
        }
#pragma unroll
        for (int m = 0; m < 4; ++m) {
#pragma unroll
            for (int j = 0; j < 4; ++j) {
                const int lr = wr*64 + m*16 + lg*4 + j;
                float ps = 0.f, pd = 0.f;
#pragma unroll
                for (int n = 0; n < 4; ++n) {
                    const int col = wc*64 + n*16 + lm;
                    const float v = acc[m][n][j];
                    ps += v * asv[n]; pd += v * adv[n];
                    hb_out[(size_t)(row0 + lr) * 256 + col] = f2us(v + bgv[n]);
                }
#pragma unroll
                for (int off = 1; off < 16; off <<= 1) {
                    ps += __shfl_xor(ps, off);
                    pd += __shfl_xor(pd, off);
                }
                if (lm == 0) { atomicAdd(&red0[lr], ps); atomicAdd(&red1[lr], pd); }
            }
        }
        __syncthreads();
        if (tid < 128) { al_s[row0 + tid] = red0[tid]; al_d[row0 + tid] = red1[tid]; }
    } else {
        if (tid < 128) red0[tid] = 0.f;
        __syncthreads();
        float bv[4];
#pragma unroll
        for (int n = 0; n < 4; ++n) bv[n] = bias[wc*64 + n*16 + lm];
#pragma unroll
        for (int m = 0; m < 4; ++m) {
#pragma unroll
            for (int j = 0; j < 4; ++j) {
                const int lr = wr*64 + m*16 + lg*4 + j;
                float ss = 0.f;
#pragma unroll
                for (int n = 0; n < 4; ++n) {
                    const float v = acc[m][n][j] + bv[n];
                    acc[m][n][j] = v;
                    ss += v * v;
                }
#pragma unroll
                for (int off = 1; off < 16; off <<= 1) ss += __shfl_xor(ss, off);
                if (lm == 0) atomicAdd(&red0[lr], ss);
            }
        }
        __syncthreads();
#pragma unroll
        for (int m = 0; m < 4; ++m) {
#pragma unroll
            for (int j = 0; j < 4; ++j) {
                const int lr = wr*64 + m*16 + lg*4 + j;
                const int grow = row0 + lr;
                if (grow < M) {
                    const float inv = 1.0f / fmaxf(sqrtf(red0[lr]), 1e-12f);
#pragma unroll
                    for (int n = 0; n < 4; ++n)
                        outp[(size_t)grow * 256 + wc*64 + n*16 + lm] = acc[m][n][j] * inv;
                }
            }
        }
    }
}

// ---------------------------------------------------------------------------
// CSR build over dst1 (scatter fused with src + edge-logit precompute)
// ---------------------------------------------------------------------------
__global__ void edge_count(const int* __restrict__ dst, int* __restrict__ cnt, int E)
{
    const int i = blockIdx.x * 256 + threadIdx.x;
    if (i < E) atomicAdd(&cnt[dst[i]], 1);
}

__global__ __launch_bounds__(1024) void scan_excl(
    const int* __restrict__ cnt, int* __restrict__ ptr, int n)
{
    __shared__ int part[1024];
    const int tid = threadIdx.x;
    const int chunk = (n + 1023) / 1024;
    const int i0 = tid * chunk;
    const int i1 = min(i0 + chunk, n);
    int s = 0;
    for (int i = i0; i < i1; ++i) s += cnt[i];
    part[tid] = s;
    __syncthreads();
    for (int off = 1; off < 1024; off <<= 1) {
        const int t = (tid >= off) ? part[tid - off] : 0;
        __syncthreads();
        part[tid] += t;
        __syncthreads();
    }
    int run = tid ? part[tid - 1] : 0;
    for (int i = i0; i < i1; ++i) { ptr[i] = run; run += cnt[i]; }
    if (tid == 1023) ptr[n] = part[1023];
}

__global__ void edge_scatter(const int* __restrict__ src, const int* __restrict__ dst,
                             const int* __restrict__ ptr, int* __restrict__ cursor,
                             const float* __restrict__ al_s, const float* __restrict__ al_d,
                             int* __restrict__ ssort, float* __restrict__ elog, int E)
{
    const int i = blockIdx.x * 256 + threadIdx.x;
    if (i < E) {
        const int d = dst[i];
        const int s = src[i];
        const int pos = ptr[d] + atomicAdd(&cursor[d], 1);
        ssort[pos] = s;
        elog[pos] = lrelu02(al_s[s] + al_d[d]);
    }
}

// ---------------------------------------------------------------------------
// Fused GAT softmax-aggregation + SAGE partial sum over s>=ND neighbors.
// Block=256: 8 slots x 32 lanes; lane holds 8 channels. Softmax stats
// computed redundantly per-thread (no barriers). hb rows are loaded ONCE and
// feed both the gat-weighted sum and (if s>=ND) the plain sage sum.
// Writes h1a (bf16, bias included via hb=h+bg) into hcat[:,256:512] and
// the s>=ND partial sum (f32) into psum.
// ---------------------------------------------------------------------------
__global__ __launch_bounds__(256) void gat_sage(
    const unsigned short* __restrict__ hb, const float* __restrict__ al_s,
    const float* __restrict__ al_d, const int* __restrict__ ssort,
    const float* __restrict__ elog, const int* __restrict__ ptr,
    unsigned short* __restrict__ hcat, float* __restrict__ psum)
{
    __shared__ float ldsg[8][264];
    __shared__ float ldss[8][264];
    const int v    = blockIdx.x;
    const int tid  = threadIdx.x;
    const int slot = tid >> 5;
    const int l32  = tid & 31;
    const int c0   = l32 * 8;
    const int p0 = ptr[v], p1 = ptr[v + 1];

    const float e_self = lrelu02(al_s[v] + al_d[v]);
    float m = e_self;
    for (int p = p0; p < p1; ++p) m = fmaxf(m, elog[p]);
    float z = __expf(e_self - m);
    for (int p = p0; p < p1; ++p) z += __expf(elog[p] - m);
    const float inv_z = 1.0f / z;

    float accg[8], accs[8];
#pragma unroll
    for (int j = 0; j < 8; ++j) accs[j] = 0.f;
    if (slot == 0) {
        const float ws = __expf(e_self - m);
        const ushort8v hv = *(const ushort8v*)&hb[(size_t)v * 256 + c0];
#pragma unroll
        for (int j = 0; j < 8; ++j) accg[j] = ws * us2f(hv[j]);
    } else {
#pragma unroll
        for (int j = 0; j < 8; ++j) accg[j] = 0.f;
    }
    for (int p = p0 + slot; p < p1; p += 8) {
        const int s = ssort[p];
        const float w = __expf(elog[p] - m);
        const ushort8v hv = *(const ushort8v*)&hb[(size_t)s * 256 + c0];
        const bool ge = (s >= ND);
#pragma unroll
        for (int j = 0; j < 8; ++j) {
            const float f = us2f(hv[j]);
            accg[j] = fmaf(w, f, accg[j]);
            accs[j] += ge ? f : 0.f;
        }
    }
    *(f32x4*)&ldsg[slot][c0]     = (f32x4){accg[0], accg[1], accg[2], accg[3]};
    *(f32x4*)&ldsg[slot][c0 + 4] = (f32x4){accg[4], accg[5], accg[6], accg[7]};
    *(f32x4*)&ldss[slot][c0]     = (f32x4){accs[0], accs[1], accs[2], accs[3]};
    *(f32x4*)&ldss[slot][c0 + 4] = (f32x4){accs[4], accs[5], accs[6], accs[7]};
    __syncthreads();

    const int c = tid;
    float rg = 0.f, rs = 0.f;
#pragma unroll
    for (int s2 = 0; s2 < 8; ++s2) { rg += ldsg[s2][c]; rs += ldss[s2][c]; }
    hcat[(size_t)v * 512 + 256 + c] = f2us(rg * inv_z);
    psum[(size_t)v * 256 + c] = rs;
}

// ---------------------------------------------------------------------------
// SAGE finisher: add s<ND neighbors (h1a rows from hcat) to psum, divide by
// degree, write mean (bf16) into hcat[:,0:256]. 4 dst per 256-thr block;
// each dst = 1 wave = 2 slots x 32 lanes; cross-slot reduce via shfl_xor(32).
// ---------------------------------------------------------------------------
__global__ __launch_bounds__(256) void sage_fin(
    const float* __restrict__ psum, const int* __restrict__ ssort,
    const int* __restrict__ ptr, unsigned short* __restrict__ hcat)
{
    const int tid   = threadIdx.x;
    const int g     = tid >> 6;                 // 0..3 (one wave per dst)
    const int v     = blockIdx.x * 4 + g;
    const int slot2 = (tid >> 5) & 1;
    const int l32   = tid & 31;
    const int c0    = l32 * 8;
    const int p0 = ptr[v], p1 = ptr[v + 1];

    float acc[8];
    if (slot2 == 0) {
        const f32x4 a0 = *(const f32x4*)&psum[(size_t)v * 256 + c0];
        const f32x4 a1 = *(const f32x4*)&psum[(size_t)v * 256 + c0 + 4];
        acc[0]=a0[0]; acc[1]=a0[1]; acc[2]=a0[2]; acc[3]=a0[3];
        acc[4]=a1[0]; acc[5]=a1[1]; acc[6]=a1[2]; acc[7]=a1[3];
    } else {
#pragma unroll
        for (int j = 0; j < 8; ++j) acc[j] = 0.f;
    }
    for (int p = p0 + slot2; p < p1; p += 2) {
        const int s = ssort[p];
        if (s < ND) {
            const ushort8v hv = *(const ushort8v*)&hcat[(size_t)s * 512 + 256 + c0];
#pragma unroll
            for (int j = 0; j < 8; ++j) acc[j] += us2f(hv[j]);
        }
    }
#pragma unroll
    for (int j = 0; j < 8; ++j) acc[j] += __shfl_xor(acc[j], 32);

    const int deg = p1 - p0;
    const float inv = (deg > 0) ? 1.0f / (float)deg : 0.f;
    if (slot2 == 0) {
        ushort8v o;
#pragma unroll
        for (int j = 0; j < 8; ++j) o[j] = f2us(acc[j] * inv);
        *(ushort8v*)&hcat[(size_t)v * 512 + c0] = o;
    }
}

// ---------------------------------------------------------------------------
extern "C" void kernel_launch(void* const* d_in, const int* in_sizes, int n_in,
                              void* d_out, int out_size, void* d_ws, size_t ws_size,
                              hipStream_t stream)
{
    const float* x    = (const float*)d_in[0];
    const float* Wg   = (const float*)d_in[1];
    const float* asrc = (const float*)d_in[2];
    const float* adst = (const float*)d_in[3];
    const float* bg   = (const float*)d_in[4];
    const float* Wl1  = (const float*)d_in[8];
    const float* bl1  = (const float*)d_in[9];
    const float* Wr1  = (const float*)d_in[10];
    const int*   src1 = (const int*)d_in[13];
    const int*   dst1 = (const int*)d_in[14];
    const int E1 = in_sizes[13];

    // workspace (cnt+cursor adjacent so one zero pass covers both)
    char* w = (char*)d_ws;
    unsigned short* hb   = (unsigned short*)w; w += (size_t)NS * 256 * 2;   // 40.96 MB
    unsigned short* hcat = (unsigned short*)w; w += (size_t)ND * 512 * 2;   // 20.48 MB
    float* psum = (float*)w; w += (size_t)ND * 256 * 4;                     // 20.48 MB
    unsigned short* Wgt  = (unsigned short*)w; w += 256 * 256 * 2;
    unsigned short* Wcat = (unsigned short*)w; w += 256 * 512 * 2;
    float* al_s = (float*)w; w += (size_t)NS * 4;
    float* al_d = (float*)w; w += (size_t)NS * 4;
    int* cnt    = (int*)w;   w += (size_t)ND * 4;
    int* cursor = (int*)w;   w += (size_t)ND * 4;
    int* ptrv   = (int*)w;   w += (size_t)(ND + 4) * 4;
    int* ssort  = (int*)w;   w += (size_t)E1 * 4;
    float* elog = (float*)w; w += (size_t)E1 * 4;

    const dim3 b256(256), b512(512);
    const int nz4 = 2 * ND / 4;   // cnt+cursor in int4s

    prep_misc<<<dim3(512 + (nz4 + 255) / 256), b256, 0, stream>>>(
        Wg, Wl1, Wr1, Wgt, Wcat, cnt, nz4);

    // h = x @ Wg + bg (bf16) with fused pre-bias al_s/al_d
    gemm_mfma<0, true><<<dim3(NS / 128), b512, 0, stream>>>(
        x, Wgt, NS, 256, hb, asrc, adst, al_s, al_d, bg, nullptr);

    // CSR over dst1 with fused edge logits
    edge_count  <<<dim3((E1 + 255) / 256), b256, 0, stream>>>(dst1, cnt, E1);
    scan_excl   <<<dim3(1), dim3(1024), 0, stream>>>(cnt, ptrv, ND);
    edge_scatter<<<dim3((E1 + 255) / 256), b256, 0, stream>>>(
        src1, dst1, ptrv, cursor, al_s, al_d, ssort, elog, E1);

    // fused GAT aggregate + SAGE s>=ND partial sum
    gat_sage<<<dim3(ND), b256, 0, stream>>>(hb, al_s, al_d, ssort, elog, ptrv,
                                            hcat, psum);
    // SAGE finisher: s<ND h1a gathers + divide
    sage_fin<<<dim3(ND / 4), b256, 0, stream>>>(psum, ssort, ptrv, hcat);

    // out = normalize([mean|h1a] @ [Wl1;Wr1] + bl1)
    gemm_mfma<1, false><<<dim3((ND + 127) / 128), b512, 0, stream>>>(
        hcat, Wcat, ND, 512, nullptr, nullptr, nullptr, nullptr, nullptr,
        bl1, (float*)d_out);
}

// Round 6
// 191.321 us; speedup vs baseline: 2.8966x; 1.0546x over previous
//
#include <hip/hip_runtime.h>

// H=256, N1=80000, N2=20000, E1=300000. Layer 0 of the reference is dead code.
// Pipeline: prep (zero cnt/cursor + weight transpose/cast) ->
// gemm0 h=x@Wg+bg (bf16 MFMA, fused al_s/al_d epilogue; edge_count fused as
// extra blocks) -> scan -> edge_scatter (fused edge logits) ->
// fused GAT-softmax-aggregate + SAGE partial-sum (s>=ND, bf16 in-place) ->
// SAGE finisher (s<ND h1a gathers) -> fused [mean|h1a]@[Wl1;Wr1]+bias+rownorm.
// bg folding: softmax coefs sum to 1, so aggregating (h+bg) gives gat+bg
// directly, and sage's s>=ND term needs h+bg anyway.

#define NS 80000
#define ND 20000

typedef float   float4v  __attribute__((ext_vector_type(4)));
typedef float   f32x4    __attribute__((ext_vector_type(4)));
typedef __bf16  bf16x8   __attribute__((ext_vector_type(8)));
typedef unsigned short ushort8v __attribute__((ext_vector_type(8)));
typedef int     int4v    __attribute__((ext_vector_type(4)));

union frag_u { ushort8v u; bf16x8 b; };

__device__ __forceinline__ float us2f(unsigned short u) {
    union { unsigned int i; float f; } x; x.i = ((unsigned)u) << 16; return x.f;
}
__device__ __forceinline__ unsigned short f2us(float f) {
    union { __bf16 b; unsigned short u; } x; x.b = (__bf16)f; return x.u;
}
__device__ __forceinline__ float lrelu02(float x) { return x > 0.f ? x : 0.2f * x; }

// ---------------------------------------------------------------------------
// prep: blocks 0..255 -> Wgt; 256..511 -> Wcat; 512.. -> zero cnt+cursor
// ---------------------------------------------------------------------------
__global__ __launch_bounds__(256) void prep_misc(
    const float* __restrict__ Wg, const float* __restrict__ Wl,
    const float* __restrict__ Wr, unsigned short* __restrict__ Wgt,
    unsigned short* __restrict__ Wcat, int* __restrict__ zerop, int nz4)
{
    const int b = blockIdx.x, t = threadIdx.x;
    if (b < 256) {
        Wgt[b * 256 + t] = f2us(Wg[t * 256 + b]);
    } else if (b < 512) {
        const int n = b - 256;
        Wcat[n * 512 + t]       = f2us(Wl[t * 256 + n]);
        Wcat[n * 512 + 256 + t] = f2us(Wr[t * 256 + n]);
    } else {
        const int i = (b - 512) * 256 + t;
        if (i < nz4) ((int4v*)zerop)[i] = (int4v){0, 0, 0, 0};
    }
}

// ---------------------------------------------------------------------------
// bf16 MFMA GEMM: C[M,256] = A[M,K] @ Bt[256,K]^T
// Block: 512 thr (8 waves, 2x4), tile 128x256, BK=32 (padded LDS stride 40).
// EPI=0: write bf16 (h+bg) + fused al_s/al_d dot-products (pre-bias).
//        COUNT: blocks >= nblk do edge_count for the CSR build instead.
// EPI=1: +bias, row-L2-normalize, write f32 out (rows guarded by M).
// AF32:  A is f32, converted to bf16 during staging (x is read only once).
// ---------------------------------------------------------------------------
template <int EPI, bool AF32, bool COUNT>
__global__ __launch_bounds__(512) void gemm_mfma(
    const void* __restrict__ Av, const unsigned short* __restrict__ Bt,
    int M, int K,
    unsigned short* __restrict__ hb_out,
    const float* __restrict__ avs, const float* __restrict__ avd,
    float* __restrict__ al_s, float* __restrict__ al_d,
    const float* __restrict__ bias, float* __restrict__ outp,
    int nblk, const int* __restrict__ dstE, int* __restrict__ cnt, int E)
{
    __shared__ __align__(16) unsigned short Als[128][40];
    __shared__ __align__(16) unsigned short Bls[256][40];
    __shared__ float red0[128];
    __shared__ float red1[128];

    if (COUNT && (int)blockIdx.x >= nblk) {
        const int i = ((int)blockIdx.x - nblk) * 512 + (int)threadIdx.x;
        if (i < E) atomicAdd(&cnt[dstE[i]], 1);
        return;
    }

    const int tid  = threadIdx.x;
    const int lane = tid & 63;
    const int wid  = tid >> 6;
    const int wr   = wid >> 2;      // 0..1
    const int wc   = wid & 3;       // 0..3
    const int row0 = blockIdx.x * 128;
    const int lg   = lane >> 4;     // 0..3
    const int lm   = lane & 15;

    f32x4 acc[4][4] = {};

    const int arow = tid >> 2;          // 0..127
    const int akof = (tid & 3) * 8;     // 0,8,16,24
    const int brow = tid >> 1;          // 0..255
    const int bkof = (tid & 1) * 16;    // 0,16

    for (int k0 = 0; k0 < K; k0 += 32) {
        {
            const int grow = row0 + arow;
            ushort8v av;
            if constexpr (AF32) {
                const float* ag = (const float*)Av + (size_t)grow * K + k0 + akof;
                const float4v v0 = *(const float4v*)ag;
                const float4v v1 = *(const float4v*)(ag + 4);
                av[0]=f2us(v0[0]); av[1]=f2us(v0[1]); av[2]=f2us(v0[2]); av[3]=f2us(v0[3]);
                av[4]=f2us(v1[0]); av[5]=f2us(v1[1]); av[6]=f2us(v1[2]); av[7]=f2us(v1[3]);
            } else {
                if (grow < M) {
                    av = *(const ushort8v*)((const unsigned short*)Av + (size_t)grow * K + k0 + akof);
                } else {
                    av = (ushort8v){0,0,0,0,0,0,0,0};
                }
            }
            *(ushort8v*)&Als[arow][akof] = av;
        }
        {
            const unsigned short* bg = Bt + (size_t)brow * K + k0 + bkof;
            *(ushort8v*)&Bls[brow][bkof]     = *(const ushort8v*)bg;
            *(ushort8v*)&Bls[brow][bkof + 8] = *(const ushort8v*)(bg + 8);
        }
        __syncthreads();

        frag_u af[4], bf[4];
#pragma unroll
        for (int m = 0; m < 4; ++m)
            af[m].u = *(const ushort8v*)&Als[wr*64 + m*16 + lm][lg*8];
#pragma unroll
        for (int n = 0; n < 4; ++n)
            bf[n].u = *(const ushort8v*)&Bls[wc*64 + n*16 + lm][lg*8];
#pragma unroll
        for (int m = 0; m < 4; ++m)
#pragma unroll
            for (int n = 0; n < 4; ++n)
                acc[m][n] = __builtin_amdgcn_mfma_f32_16x16x32_bf16(
                    af[m].b, bf[n].b, acc[m][n], 0, 0, 0);
        __syncthreads();
    }

    if constexpr (EPI == 0) {
        if (tid < 128) { red0[tid] = 0.f; red1[tid] = 0.f; }
        __syncthreads();
        float asv[4], adv[4], bgv[4];
#pragma unroll
        for (int n = 0; n < 4; ++n) {
            const int col = wc*64 + n*16 + lm;
            asv[n] = avs[col]; adv[n] = avd[col]; bgv[n] = bias[col];
        }
#pragma unroll
        for (int m = 0; m < 4; ++m) {
#pragma unroll
            for (int j = 0; j < 4; ++j) {
                const int lr = wr*64 + m*16 + lg*4 + j;
                float ps = 0.f, pd = 0.f;
#pragma unroll
                for (int n = 0; n < 4; ++n) {
                    const int col = wc*64 + n*16 + lm;
                    const float v = acc[m][n][j];
                    ps += v * asv[n]; pd += v * adv[n];
                    hb_out[(size_t)(row0 + lr) * 256 + col] = f2us(v + bgv[n]);
                }
#pragma unroll
                for (int off = 1; off < 16; off <<= 1) {
                    ps += __shfl_xor(ps, off);
                    pd += __shfl_xor(pd, off);
                }
                if (lm == 0) { atomicAdd(&red0[lr], ps); atomicAdd(&red1[lr], pd); }
            }
        }
        __syncthreads();
        if (tid < 128) { al_s[row0 + tid] = red0[tid]; al_d[row0 + tid] = red1[tid]; }
    } else {
        if (tid < 128) red0[tid] = 0.f;
        __syncthreads();
        float bv[4];
#pragma unroll
        for (int n = 0; n < 4; ++n) bv[n] = bias[wc*64 + n*16 + lm];
#pragma unroll
        for (int m = 0; m < 4; ++m) {
#pragma unroll
            for (int j = 0; j < 4; ++j) {
                const int lr = wr*64 + m*16 + lg*4 + j;
                float ss = 0.f;
#pragma unroll
                for (int n = 0; n < 4; ++n) {
                    const float v = acc[m][n][j] + bv[n];
                    acc[m][n][j] = v;
                    ss += v * v;
                }
#pragma unroll
                for (int off = 1; off < 16; off <<= 1) ss += __shfl_xor(ss, off);
                if (lm == 0) atomicAdd(&red0[lr], ss);
            }
        }
        __syncthreads();
#pragma unroll
        for (int m = 0; m < 4; ++m) {
#pragma unroll
            for (int j = 0; j < 4; ++j) {
                const int lr = wr*64 + m*16 + lg*4 + j;
                const int grow = row0 + lr;
                if (grow < M) {
                    const float inv = 1.0f / fmaxf(sqrtf(red0[lr]), 1e-12f);
#pragma unroll
                    for (int n = 0; n < 4; ++n)
                        outp[(size_t)grow * 256 + wc*64 + n*16 + lm] = acc[m][n][j] * inv;
                }
            }
        }
    }
}

// ---------------------------------------------------------------------------
// CSR: scan + scatter (scatter fused with src + edge-logit precompute)
// ---------------------------------------------------------------------------
__global__ __launch_bounds__(1024) void scan_excl(
    const int* __restrict__ cnt, int* __restrict__ ptr, int n)
{
    __shared__ int part[1024];
    const int tid = threadIdx.x;
    const int chunk = (n + 1023) / 1024;
    const int i0 = tid * chunk;
    const int i1 = min(i0 + chunk, n);
    int s = 0;
    for (int i = i0; i < i1; ++i) s += cnt[i];
    part[tid] = s;
    __syncthreads();
    for (int off = 1; off < 1024; off <<= 1) {
        const int t = (tid >= off) ? part[tid - off] : 0;
        __syncthreads();
        part[tid] += t;
        __syncthreads();
    }
    int run = tid ? part[tid - 1] : 0;
    for (int i = i0; i < i1; ++i) { ptr[i] = run; run += cnt[i]; }
    if (tid == 1023) ptr[n] = part[1023];
}

__global__ void edge_scatter(const int* __restrict__ src, const int* __restrict__ dst,
                             const int* __restrict__ ptr, int* __restrict__ cursor,
                             const float* __restrict__ al_s, const float* __restrict__ al_d,
                             int* __restrict__ ssort, float* __restrict__ elog, int E)
{
    const int i = blockIdx.x * 256 + threadIdx.x;
    if (i < E) {
        const int d = dst[i];
        const int s = src[i];
        const int pos = ptr[d] + atomicAdd(&cursor[d], 1);
        ssort[pos] = s;
        elog[pos] = lrelu02(al_s[s] + al_d[d]);
    }
}

// ---------------------------------------------------------------------------
// Fused GAT softmax-aggregation + SAGE partial sum over s>=ND neighbors.
// Block=256: 8 slots x 32 lanes; lane holds 8 channels. Softmax stats
// computed redundantly per-thread (no barriers). hb rows are loaded ONCE and
// feed both the gat-weighted sum and (if s>=ND) the plain sage sum.
// Writes h1a (bf16, bias included via hb=h+bg) into hcat[:,256:512] and the
// s>=ND partial sum (bf16) in-place into hcat[:,0:256] (finished by sage_fin).
// ---------------------------------------------------------------------------
__global__ __launch_bounds__(256) void gat_sage(
    const unsigned short* __restrict__ hb, const float* __restrict__ al_s,
    const float* __restrict__ al_d, const int* __restrict__ ssort,
    const float* __restrict__ elog, const int* __restrict__ ptr,
    unsigned short* __restrict__ hcat)
{
    __shared__ float ldsg[8][264];
    __shared__ float ldss[8][264];
    const int v    = blockIdx.x;
    const int tid  = threadIdx.x;
    const int slot = tid >> 5;
    const int l32  = tid & 31;
    const int c0   = l32 * 8;
    const int p0 = ptr[v], p1 = ptr[v + 1];

    const float e_self = lrelu02(al_s[v] + al_d[v]);
    float m = e_self;
    for (int p = p0; p < p1; ++p) m = fmaxf(m, elog[p]);
    float z = __expf(e_self - m);
    for (int p = p0; p < p1; ++p) z += __expf(elog[p] - m);
    const float inv_z = 1.0f / z;

    float accg[8], accs[8];
#pragma unroll
    for (int j = 0; j < 8; ++j) accs[j] = 0.f;
    if (slot == 0) {
        const float ws = __expf(e_self - m);
        const ushort8v hv = *(const ushort8v*)&hb[(size_t)v * 256 + c0];
#pragma unroll
        for (int j = 0; j < 8; ++j) accg[j] = ws * us2f(hv[j]);
    } else {
#pragma unroll
        for (int j = 0; j < 8; ++j) accg[j] = 0.f;
    }
    for (int p = p0 + slot; p < p1; p += 8) {
        const int s = ssort[p];
        const float w = __expf(elog[p] - m);
        const ushort8v hv = *(const ushort8v*)&hb[(size_t)s * 256 + c0];
        const bool ge = (s >= ND);
#pragma unroll
        for (int j = 0; j < 8; ++j) {
            const float f = us2f(hv[j]);
            accg[j] = fmaf(w, f, accg[j]);
            accs[j] += ge ? f : 0.f;
        }
    }
    *(f32x4*)&ldsg[slot][c0]     = (f32x4){accg[0], accg[1], accg[2], accg[3]};
    *(f32x4*)&ldsg[slot][c0 + 4] = (f32x4){accg[4], accg[5], accg[6], accg[7]};
    *(f32x4*)&ldss[slot][c0]     = (f32x4){accs[0], accs[1], accs[2], accs[3]};
    *(f32x4*)&ldss[slot][c0 + 4] = (f32x4){accs[4], accs[5], accs[6], accs[7]};
    __syncthreads();

    const int c = tid;
    float rg = 0.f, rs = 0.f;
#pragma unroll
    for (int s2 = 0; s2 < 8; ++s2) { rg += ldsg[s2][c]; rs += ldss[s2][c]; }
    hcat[(size_t)v * 512 + 256 + c] = f2us(rg * inv_z);
    hcat[(size_t)v * 512 + c]       = f2us(rs);      // psum (pre-mean)
}

// ---------------------------------------------------------------------------
// SAGE finisher: psum (bf16, in hcat[:,0:256]) += s<ND h1a gathers; divide by
// degree; write mean back in place. 4 dst per 256-thr block; each dst = 1
// wave = 2 slots x 32 lanes; cross-slot reduce via shfl_xor(32).
// ---------------------------------------------------------------------------
__global__ __launch_bounds__(256) void sage_fin(
    const int* __restrict__ ssort, const int* __restrict__ ptr,
    unsigned short* __restrict__ hcat)
{
    const int tid   = threadIdx.x;
    const int g     = tid >> 6;                 // 0..3 (one wave per dst)
    const int v     = blockIdx.x * 4 + g;
    const int slot2 = (tid >> 5) & 1;
    const int l32   = tid & 31;
    const int c0    = l32 * 8;
    const int p0 = ptr[v], p1 = ptr[v + 1];

    float acc[8];
    if (slot2 == 0) {
        const ushort8v pv = *(const ushort8v*)&hcat[(size_t)v * 512 + c0];
#pragma unroll
        for (int j = 0; j < 8; ++j) acc[j] = us2f(pv[j]);
    } else {
#pragma unroll
        for (int j = 0; j < 8; ++j) acc[j] = 0.f;
    }
    for (int p = p0 + slot2; p < p1; p += 2) {
        const int s = ssort[p];
        if (s < ND) {
            const ushort8v hv = *(const ushort8v*)&hcat[(size_t)s * 512 + 256 + c0];
#pragma unroll
            for (int j = 0; j < 8; ++j) acc[j] += us2f(hv[j]);
        }
    }
#pragma unroll
    for (int j = 0; j < 8; ++j) acc[j] += __shfl_xor(acc[j], 32);

    const int deg = p1 - p0;
    const float inv = (deg > 0) ? 1.0f / (float)deg : 0.f;
    if (slot2 == 0) {
        ushort8v o;
#pragma unroll
        for (int j = 0; j < 8; ++j) o[j] = f2us(acc[j] * inv);
        *(ushort8v*)&hcat[(size_t)v * 512 + c0] = o;
    }
}

// ---------------------------------------------------------------------------
extern "C" void kernel_launch(void* const* d_in, const int* in_sizes, int n_in,
                              void* d_out, int out_size, void* d_ws, size_t ws_size,
                              hipStream_t stream)
{
    const float* x    = (const float*)d_in[0];
    const float* Wg   = (const float*)d_in[1];
    const float* asrc = (const float*)d_in[2];
    const float* adst = (const float*)d_in[3];
    const float* bg   = (const float*)d_in[4];
    const float* Wl1  = (const float*)d_in[8];
    const float* bl1  = (const float*)d_in[9];
    const float* Wr1  = (const float*)d_in[10];
    const int*   src1 = (const int*)d_in[13];
    const int*   dst1 = (const int*)d_in[14];
    const int E1 = in_sizes[13];

    // workspace (cnt+cursor adjacent so one zero pass covers both)
    char* w = (char*)d_ws;
    unsigned short* hb   = (unsigned short*)w; w += (size_t)NS * 256 * 2;   // 40.96 MB
    unsigned short* hcat = (unsigned short*)w; w += (size_t)ND * 512 * 2;   // 20.48 MB
    unsigned short* Wgt  = (unsigned short*)w; w += 256 * 256 * 2;
    unsigned short* Wcat = (unsigned short*)w; w += 256 * 512 * 2;
    float* al_s = (float*)w; w += (size_t)NS * 4;
    float* al_d = (float*)w; w += (size_t)NS * 4;
    int* cnt    = (int*)w;   w += (size_t)ND * 4;
    int* cursor = (int*)w;   w += (size_t)ND * 4;
    int* ptrv   = (int*)w;   w += (size_t)(ND + 4) * 4;
    int* ssort  = (int*)w;   w += (size_t)E1 * 4;
    float* elog = (float*)w; w += (size_t)E1 * 4;

    const dim3 b256(256), b512(512);
    const int nz4 = 2 * ND / 4;   // cnt+cursor in int4s

    prep_misc<<<dim3(512 + (nz4 + 255) / 256), b256, 0, stream>>>(
        Wg, Wl1, Wr1, Wgt, Wcat, cnt, nz4);

    // h = x @ Wg + bg (bf16) with fused pre-bias al_s/al_d; edge_count fused
    const int nblk0 = NS / 128;
    const int ncnt  = (E1 + 511) / 512;
    gemm_mfma<0, true, true><<<dim3(nblk0 + ncnt), b512, 0, stream>>>(
        x, Wgt, NS, 256, hb, asrc, adst, al_s, al_d, bg, nullptr,
        nblk0, dst1, cnt, E1);

    scan_excl   <<<dim3(1), dim3(1024), 0, stream>>>(cnt, ptrv, ND);
    edge_scatter<<<dim3((E1 + 255) / 256), b256, 0, stream>>>(
        src1, dst1, ptrv, cursor, al_s, al_d, ssort, elog, E1);

    // fused GAT aggregate + SAGE s>=ND partial sum (psum bf16 in-place)
    gat_sage<<<dim3(ND), b256, 0, stream>>>(hb, al_s, al_d, ssort, elog, ptrv,
                                            hcat);
    // SAGE finisher: s<ND h1a gathers + divide
    sage_fin<<<dim3(ND / 4), b256, 0, stream>>>(ssort, ptrv, hcat);

    // out = normalize([mean|h1a] @ [Wl1;Wr1] + bl1)
    gemm_mfma<1, false, false><<<dim3((ND + 127) / 128), b512, 0, stream>>>(
        hcat, Wcat, ND, 512, nullptr, nullptr, nullptr, nullptr, nullptr,
        bl1, (float*)d_out, 0, nullptr, nullptr, 0);
}

// Round 7
// 182.248 us; speedup vs baseline: 3.0408x; 1.0498x over previous
//
#include <hip/hip_runtime.h>

// H=256, N1=80000, N2=20000, E1=300000. Layer 0 of the reference is dead code.
// Pipeline: prep (zero cnt/cursor + weight transpose/cast) ->
// gemm0 h=x@Wg+bg (bf16 MFMA, dbuf-pipelined, fused al_s/al_d epilogue;
// edge_count fused as extra blocks) -> scan -> edge_scatter (fused edge
// logits) -> fused GAT-softmax-aggregate + SAGE partial-sum (s>=ND) with
// wave-cooperative softmax stats -> SAGE finisher (s<ND h1a gathers) ->
// fused [mean|h1a]@[Wl1;Wr1]+bias+rownorm (dbuf-pipelined).
// bg folding: softmax coefs sum to 1, so aggregating (h+bg) gives gat+bg
// directly, and sage's s>=ND term needs h+bg anyway.

#define NS 80000
#define ND 20000
#define DCAP 1024   // cached softmax weights per dst (fallback recompute past)

typedef float   float4v  __attribute__((ext_vector_type(4)));
typedef float   f32x4    __attribute__((ext_vector_type(4)));
typedef __bf16  bf16x8   __attribute__((ext_vector_type(8)));
typedef unsigned short ushort8v __attribute__((ext_vector_type(8)));
typedef int     int4v    __attribute__((ext_vector_type(4)));

union frag_u { ushort8v u; bf16x8 b; };

__device__ __forceinline__ float us2f(unsigned short u) {
    union { unsigned int i; float f; } x; x.i = ((unsigned)u) << 16; return x.f;
}
__device__ __forceinline__ unsigned short f2us(float f) {
    union { __bf16 b; unsigned short u; } x; x.b = (__bf16)f; return x.u;
}
__device__ __forceinline__ float lrelu02(float x) { return x > 0.f ? x : 0.2f * x; }

// ---------------------------------------------------------------------------
// prep: blocks 0..255 -> Wgt; 256..511 -> Wcat; 512.. -> zero cnt+cursor
// ---------------------------------------------------------------------------
__global__ __launch_bounds__(256) void prep_misc(
    const float* __restrict__ Wg, const float* __restrict__ Wl,
    const float* __restrict__ Wr, unsigned short* __restrict__ Wgt,
    unsigned short* __restrict__ Wcat, int* __restrict__ zerop, int nz4)
{
    const int b = blockIdx.x, t = threadIdx.x;
    if (b < 256) {
        Wgt[b * 256 + t] = f2us(Wg[t * 256 + b]);
    } else if (b < 512) {
        const int n = b - 256;
        Wcat[n * 512 + t]       = f2us(Wl[t * 256 + n]);
        Wcat[n * 512 + 256 + t] = f2us(Wr[t * 256 + n]);
    } else {
        const int i = (b - 512) * 256 + t;
        if (i < nz4) ((int4v*)zerop)[i] = (int4v){0, 0, 0, 0};
    }
}

// ---------------------------------------------------------------------------
// bf16 MFMA GEMM: C[M,256] = A[M,K] @ Bt[256,K]^T
// Block: 512 thr (8 waves, 2x4), tile 128x256, BK=32 (padded LDS stride 40).
// Double-buffered LDS + register prefetch: 1 barrier per K-step; the global
// load for tile k+2 is issued right after the barrier so its latency hides
// under tile k+1's ds_reads + MFMAs.
// EPI=0: write bf16 (h+bg) + fused al_s/al_d dot-products (pre-bias).
//        COUNT: blocks >= nblk do edge_count for the CSR build instead.
// EPI=1: +bias, row-L2-normalize, write f32 out (rows guarded by M).
// AF32:  A is f32, converted to bf16 during staging (x is read only once).
// ---------------------------------------------------------------------------
template <int EPI, bool AF32, bool COUNT>
__global__ __launch_bounds__(512) void gemm_mfma(
    const void* __restrict__ Av, const unsigned short* __restrict__ Bt,
    int M, int K,
    unsigned short* __restrict__ hb_out,
    const float* __restrict__ avs, const float* __restrict__ avd,
    float* __restrict__ al_s, float* __restrict__ al_d,
    const float* __restrict__ bias, float* __restrict__ outp,
    int nblk, const int* __restrict__ dstE, int* __restrict__ cnt, int E)
{
    __shared__ __align__(16) unsigned short Als[2][128][40];
    __shared__ __align__(16) unsigned short Bls[2][256][40];
    __shared__ float red0[128];
    __shared__ float red1[128];

    if (COUNT && (int)blockIdx.x >= nblk) {
        const int i = ((int)blockIdx.x - nblk) * 512 + (int)threadIdx.x;
        if (i < E) atomicAdd(&cnt[dstE[i]], 1);
        return;
    }

    const int tid  = threadIdx.x;
    const int lane = tid & 63;
    const int wid  = tid >> 6;
    const int wr   = wid >> 2;      // 0..1
    const int wc   = wid & 3;       // 0..3
    const int row0 = blockIdx.x * 128;
    const int lg   = lane >> 4;     // 0..3
    const int lm   = lane & 15;

    f32x4 acc[4][4] = {};

    const int arow = tid >> 2;          // 0..127
    const int akof = (tid & 3) * 8;     // 0,8,16,24
    const int brow = tid >> 1;          // 0..255
    const int bkof = (tid & 1) * 16;    // 0,16
    const int nk   = K >> 5;

    ushort8v avr, bvr0, bvr1;

    auto load_t = [&](int kt) {
        const int k0 = kt * 32;
        if constexpr (AF32) {
            const float* ag = (const float*)Av + (size_t)(row0 + arow) * K + k0 + akof;
            const float4v v0 = *(const float4v*)ag;
            const float4v v1 = *(const float4v*)(ag + 4);
            avr[0]=f2us(v0[0]); avr[1]=f2us(v0[1]); avr[2]=f2us(v0[2]); avr[3]=f2us(v0[3]);
            avr[4]=f2us(v1[0]); avr[5]=f2us(v1[1]); avr[6]=f2us(v1[2]); avr[7]=f2us(v1[3]);
        } else {
            if (row0 + arow < M) {
                avr = *(const ushort8v*)((const unsigned short*)Av + (size_t)(row0 + arow) * K + k0 + akof);
            } else {
                avr = (ushort8v){0,0,0,0,0,0,0,0};
            }
        }
        const unsigned short* bgp = Bt + (size_t)brow * K + k0 + bkof;
        bvr0 = *(const ushort8v*)bgp;
        bvr1 = *(const ushort8v*)(bgp + 8);
    };
    auto store_t = [&](int b) {
        *(ushort8v*)&Als[b][arow][akof]     = avr;
        *(ushort8v*)&Bls[b][brow][bkof]     = bvr0;
        *(ushort8v*)&Bls[b][brow][bkof + 8] = bvr1;
    };

    load_t(0); store_t(0); __syncthreads();
    if (nk > 1) load_t(1);
    int cur = 0;

    for (int kt = 0; kt < nk; ++kt) {
        frag_u af[4], bf[4];
#pragma unroll
        for (int m = 0; m < 4; ++m)
            af[m].u = *(const ushort8v*)&Als[cur][wr*64 + m*16 + lm][lg*8];
#pragma unroll
        for (int n = 0; n < 4; ++n)
            bf[n].u = *(const ushort8v*)&Bls[cur][wc*64 + n*16 + lm][lg*8];
#pragma unroll
        for (int m = 0; m < 4; ++m)
#pragma unroll
            for (int n = 0; n < 4; ++n)
                acc[m][n] = __builtin_amdgcn_mfma_f32_16x16x32_bf16(
                    af[m].b, bf[n].b, acc[m][n], 0, 0, 0);
        if (kt + 1 < nk) {
            store_t(cur ^ 1);            // regs hold tile kt+1
            __syncthreads();
            if (kt + 2 < nk) load_t(kt + 2);
            cur ^= 1;
        }
    }

    if constexpr (EPI == 0) {
        if (tid < 128) { red0[tid] = 0.f; red1[tid] = 0.f; }
        __syncthreads();
        float asv[4], adv[4], bgv[4];
#pragma unroll
        for (int n = 0; n < 4; ++n) {
            const int col = wc*64 + n*16 + lm;
            asv[n] = avs[col]; adv[n] = avd[col]; bgv[n] = bias[col];
        }
#pragma unroll
        for (int m = 0; m < 4; ++m) {
#pragma unroll
            for (int j = 0; j < 4; ++j) {
                const int lr = wr*64 + m*16 + lg*4 + j;
                float ps = 0.f, pd = 0.f;
#pragma unroll
                for (int n = 0; n < 4; ++n) {
                    const float v = acc[m][n][j];
                    ps += v * asv[n]; pd += v * adv[n];
                    hb_out[(size_t)(row0 + lr) * 256 + wc*64 + n*16 + lm] = f2us(v + bgv[n]);
                }
#pragma unroll
                for (int off = 1; off < 16; off <<= 1) {
                    ps += __shfl_xor(ps, off);
                    pd += __shfl_xor(pd, off);
                }
                if (lm == 0) { atomicAdd(&red0[lr], ps); atomicAdd(&red1[lr], pd); }
            }
        }
        __syncthreads();
        if (tid < 128) { al_s[row0 + tid] = red0[tid]; al_d[row0 + tid] = red1[tid]; }
    } else {
        if (tid < 128) red0[tid] = 0.f;
        __syncthreads();
        float bv[4];
#pragma unroll
        for (int n = 0; n < 4; ++n) bv[n] = bias[wc*64 + n*16 + lm];
#pragma unroll
        for (int m = 0; m < 4; ++m) {
#pragma unroll
            for (int j = 0; j < 4; ++j) {
                const int lr = wr*64 + m*16 + lg*4 + j;
                float ss = 0.f;
#pragma unroll
                for (int n = 0; n < 4; ++n) {
                    const float v = acc[m][n][j] + bv[n];
                    acc[m][n][j] = v;
                    ss += v * v;
                }
#pragma unroll
                for (int off = 1; off < 16; off <<= 1) ss += __shfl_xor(ss, off);
                if (lm == 0) atomicAdd(&red0[lr], ss);
            }
        }
        __syncthreads();
#pragma unroll
        for (int m = 0; m < 4; ++m) {
#pragma unroll
            for (int j = 0; j < 4; ++j) {
                const int lr = wr*64 + m*16 + lg*4 + j;
                const int grow = row0 + lr;
                if (grow < M) {
                    const float inv = 1.0f / fmaxf(sqrtf(red0[lr]), 1e-12f);
#pragma unroll
                    for (int n = 0; n < 4; ++n)
                        outp[(size_t)grow * 256 + wc*64 + n*16 + lm] = acc[m][n][j] * inv;
                }
            }
        }
    }
}

// ---------------------------------------------------------------------------
// CSR: scan + scatter (scatter fused with src + edge-logit precompute)
// ---------------------------------------------------------------------------
__global__ __launch_bounds__(1024) void scan_excl(
    const int* __restrict__ cnt, int* __restrict__ ptr, int n)
{
    __shared__ int part[1024];
    const int tid = threadIdx.x;
    const int chunk = (n + 1023) / 1024;
    const int i0 = tid * chunk;
    const int i1 = min(i0 + chunk, n);
    int s = 0;
    for (int i = i0; i < i1; ++i) s += cnt[i];
    part[tid] = s;
    __syncthreads();
    for (int off = 1; off < 1024; off <<= 1) {
        const int t = (tid >= off) ? part[tid - off] : 0;
        __syncthreads();
        part[tid] += t;
        __syncthreads();
    }
    int run = tid ? part[tid - 1] : 0;
    for (int i = i0; i < i1; ++i) { ptr[i] = run; run += cnt[i]; }
    if (tid == 1023) ptr[n] = part[1023];
}

__global__ void edge_scatter(const int* __restrict__ src, const int* __restrict__ dst,
                             const int* __restrict__ ptr, int* __restrict__ cursor,
                             const float* __restrict__ al_s, const float* __restrict__ al_d,
                             int* __restrict__ ssort, float* __restrict__ elog, int E)
{
    const int i = blockIdx.x * 256 + threadIdx.x;
    if (i < E) {
        const int d = dst[i];
        const int s = src[i];
        const int pos = ptr[d] + atomicAdd(&cursor[d], 1);
        ssort[pos] = s;
        elog[pos] = lrelu02(al_s[s] + al_d[d]);
    }
}

// ---------------------------------------------------------------------------
// Fused GAT softmax-aggregation + SAGE partial sum over s>=ND neighbors.
// Block=256: 8 slots x 32 lanes; lane holds 8 channels.
// Softmax stats computed ONCE by wave 0 (grid-stride + butterfly reduce),
// weights exp(e-m) cached in wlds (fallback recompute for deg>DCAP).
// hb rows are loaded ONCE and feed both the gat-weighted sum and (if s>=ND)
// the plain sage sum. Writes h1a (bf16, bias included via hb=h+bg) into
// hcat[:,256:512] and the s>=ND partial sum (bf16) into hcat[:,0:256]
// (finished by sage_fin).
// ---------------------------------------------------------------------------
__global__ __launch_bounds__(256) void gat_sage(
    const unsigned short* __restrict__ hb, const float* __restrict__ al_s,
    const float* __restrict__ al_d, const int* __restrict__ ssort,
    const float* __restrict__ elog, const int* __restrict__ ptr,
    unsigned short* __restrict__ hcat)
{
    __shared__ float ldsg[8][264];
    __shared__ float ldss[8][264];
    __shared__ float wlds[DCAP];
    __shared__ float sc[2];
    const int v    = blockIdx.x;
    const int tid  = threadIdx.x;
    const int slot = tid >> 5;
    const int l32  = tid & 31;
    const int c0   = l32 * 8;
    const int p0 = ptr[v], p1 = ptr[v + 1];
    const float e_self = lrelu02(al_s[v] + al_d[v]);

    if (tid < 64) {
        float mm = e_self;
        for (int p = p0 + tid; p < p1; p += 64) mm = fmaxf(mm, elog[p]);
#pragma unroll
        for (int off = 32; off; off >>= 1) mm = fmaxf(mm, __shfl_xor(mm, off));
        float z = (tid == 0) ? __expf(e_self - mm) : 0.f;
        for (int p = p0 + tid; p < p1; p += 64) {
            const float wv = __expf(elog[p] - mm);
            const int pc = p - p0;
            if (pc < DCAP) wlds[pc] = wv;
            z += wv;
        }
#pragma unroll
        for (int off = 32; off; off >>= 1) z += __shfl_xor(z, off);
        if (tid == 0) { sc[0] = mm; sc[1] = 1.0f / z; }
    }
    __syncthreads();
    const float m     = sc[0];
    const float inv_z = sc[1];

    float accg[8], accs[8];
#pragma unroll
    for (int j = 0; j < 8; ++j) accs[j] = 0.f;
    if (slot == 0) {
        const float ws = __expf(e_self - m);
        const ushort8v hv = *(const ushort8v*)&hb[(size_t)v * 256 + c0];
#pragma unroll
        for (int j = 0; j < 8; ++j) accg[j] = ws * us2f(hv[j]);
    } else {
#pragma unroll
        for (int j = 0; j < 8; ++j) accg[j] = 0.f;
    }
    for (int p = p0 + slot; p < p1; p += 8) {
        const int s  = ssort[p];
        const int pc = p - p0;
        const float w = (pc < DCAP) ? wlds[pc] : __expf(elog[p] - m);
        const ushort8v hv = *(const ushort8v*)&hb[(size_t)s * 256 + c0];
        const bool ge = (s >= ND);
#pragma unroll
        for (int j = 0; j < 8; ++j) {
            const float f = us2f(hv[j]);
            accg[j] = fmaf(w, f, accg[j]);
            accs[j] += ge ? f : 0.f;
        }
    }
    *(f32x4*)&ldsg[slot][c0]     = (f32x4){accg[0], accg[1], accg[2], accg[3]};
    *(f32x4*)&ldsg[slot][c0 + 4] = (f32x4){accg[4], accg[5], accg[6], accg[7]};
    *(f32x4*)&ldss[slot][c0]     = (f32x4){accs[0], accs[1], accs[2], accs[3]};
    *(f32x4*)&ldss[slot][c0 + 4] = (f32x4){accs[4], accs[5], accs[6], accs[7]};
    __syncthreads();

    const int c = tid;
    float rg = 0.f, rs = 0.f;
#pragma unroll
    for (int s2 = 0; s2 < 8; ++s2) { rg += ldsg[s2][c]; rs += ldss[s2][c]; }
    hcat[(size_t)v * 512 + 256 + c] = f2us(rg * inv_z);
    hcat[(size_t)v * 512 + c]       = f2us(rs);      // psum (pre-mean)
}

// ---------------------------------------------------------------------------
// SAGE finisher: psum (bf16, in hcat[:,0:256]) += s<ND h1a gathers; divide by
// degree; write mean back in place. 4 dst per 256-thr block; each dst = 1
// wave = 2 slots x 32 lanes; cross-slot reduce via shfl_xor(32).
// ---------------------------------------------------------------------------
__global__ __launch_bounds__(256) void sage_fin(
    const int* __restrict__ ssort, const int* __restrict__ ptr,
    unsigned short* __restrict__ hcat)
{
    const int tid   = threadIdx.x;
    const int g     = tid >> 6;                 // 0..3 (one wave per dst)
    const int v     = blockIdx.x * 4 + g;
    const int slot2 = (tid >> 5) & 1;
    const int l32   = tid & 31;
    const int c0    = l32 * 8;
    const int p0 = ptr[v], p1 = ptr[v + 1];

    float acc[8];
    if (slot2 == 0) {
        const ushort8v pv = *(const ushort8v*)&hcat[(size_t)v * 512 + c0];
#pragma unroll
        for (int j = 0; j < 8; ++j) acc[j] = us2f(pv[j]);
    } else {
#pragma unroll
        for (int j = 0; j < 8; ++j) acc[j] = 0.f;
    }
    for (int p = p0 + slot2; p < p1; p += 2) {
        const int s = ssort[p];
        if (s < ND) {
            const ushort8v hv = *(const ushort8v*)&hcat[(size_t)s * 512 + 256 + c0];
#pragma unroll
            for (int j = 0; j < 8; ++j) acc[j] += us2f(hv[j]);
        }
    }
#pragma unroll
    for (int j = 0; j < 8; ++j) acc[j] += __shfl_xor(acc[j], 32);

    const int deg = p1 - p0;
    const float inv = (deg > 0) ? 1.0f / (float)deg : 0.f;
    if (slot2 == 0) {
        ushort8v o;
#pragma unroll
        for (int j = 0; j < 8; ++j) o[j] = f2us(acc[j] * inv);
        *(ushort8v*)&hcat[(size_t)v * 512 + c0] = o;
    }
}

// ---------------------------------------------------------------------------
extern "C" void kernel_launch(void* const* d_in, const int* in_sizes, int n_in,
                              void* d_out, int out_size, void* d_ws, size_t ws_size,
                              hipStream_t stream)
{
    const float* x    = (const float*)d_in[0];
    const float* Wg   = (const float*)d_in[1];
    const float* asrc = (const float*)d_in[2];
    const float* adst = (const float*)d_in[3];
    const float* bg   = (const float*)d_in[4];
    const float* Wl1  = (const float*)d_in[8];
    const float* bl1  = (const float*)d_in[9];
    const float* Wr1  = (const float*)d_in[10];
    const int*   src1 = (const int*)d_in[13];
    const int*   dst1 = (const int*)d_in[14];
    const int E1 = in_sizes[13];

    // workspace (cnt+cursor adjacent so one zero pass covers both)
    char* w = (char*)d_ws;
    unsigned short* hb   = (unsigned short*)w; w += (size_t)NS * 256 * 2;   // 40.96 MB
    unsigned short* hcat = (unsigned short*)w; w += (size_t)ND * 512 * 2;   // 20.48 MB
    unsigned short* Wgt  = (unsigned short*)w; w += 256 * 256 * 2;
    unsigned short* Wcat = (unsigned short*)w; w += 256 * 512 * 2;
    float* al_s = (float*)w; w += (size_t)NS * 4;
    float* al_d = (float*)w; w += (size_t)NS * 4;
    int* cnt    = (int*)w;   w += (size_t)ND * 4;
    int* cursor = (int*)w;   w += (size_t)ND * 4;
    int* ptrv   = (int*)w;   w += (size_t)(ND + 4) * 4;
    int* ssort  = (int*)w;   w += (size_t)E1 * 4;
    float* elog = (float*)w; w += (size_t)E1 * 4;

    const dim3 b256(256), b512(512);
    const int nz4 = 2 * ND / 4;   // cnt+cursor in int4s

    prep_misc<<<dim3(512 + (nz4 + 255) / 256), b256, 0, stream>>>(
        Wg, Wl1, Wr1, Wgt, Wcat, cnt, nz4);

    // h = x @ Wg + bg (bf16) with fused pre-bias al_s/al_d; edge_count fused
    const int nblk0 = NS / 128;
    const int ncnt  = (E1 + 511) / 512;
    gemm_mfma<0, true, true><<<dim3(nblk0 + ncnt), b512, 0, stream>>>(
        x, Wgt, NS, 256, hb, asrc, adst, al_s, al_d, bg, nullptr,
        nblk0, dst1, cnt, E1);

    scan_excl   <<<dim3(1), dim3(1024), 0, stream>>>(cnt, ptrv, ND);
    edge_scatter<<<dim3((E1 + 255) / 256), b256, 0, stream>>>(
        src1, dst1, ptrv, cursor, al_s, al_d, ssort, elog, E1);

    // fused GAT aggregate + SAGE s>=ND partial sum (psum bf16 in-place)
    gat_sage<<<dim3(ND), b256, 0, stream>>>(hb, al_s, al_d, ssort, elog, ptrv,
                                            hcat);
    // SAGE finisher: s<ND h1a gathers + divide
    sage_fin<<<dim3(ND / 4), b256, 0, stream>>>(ssort, ptrv, hcat);

    // out = normalize([mean|h1a] @ [Wl1;Wr1] + bl1)
    gemm_mfma<1, false, false><<<dim3((ND + 127) / 128), b512, 0, stream>>>(
        hcat, Wcat, ND, 512, nullptr, nullptr, nullptr, nullptr, nullptr,
        bl1, (float*)d_out, 0, nullptr, nullptr, 0);
}

// Round 8
// 163.271 us; speedup vs baseline: 3.3942x; 1.1162x over previous
//
#include <hip/hip_runtime.h>

// H=256, N1=80000, N2=20000, E1=300000. Layer 0 of the reference is dead code.
// Pipeline: prep (zero cnt/cursor + weight transpose/cast) ->
// gemm0 h=x@Wg+bg (bf16 MFMA, dbuf-pipelined, fused al_s/al_d epilogue;
// edge_count fused as extra blocks) -> scan -> edge_scatter (fused edge
// weight w=exp(lrelu(logit)); max-shift dropped: logits ~N(0,2), exp safe in
// f32 and coef=w/z is exact-ratio-identical) -> fused GAT aggregate + SAGE
// partial-sum (s>=ND), 128-thr latency-optimized -> SAGE finisher -> fused
// [mean|h1a]@[Wl1;Wr1]+bias+rownorm (dbuf-pipelined).
// bg folding: softmax coefs sum to 1, so aggregating (h+bg) gives gat+bg
// directly, and sage's s>=ND term needs h+bg anyway.

#define NS 80000
#define ND 20000

typedef float   float4v  __attribute__((ext_vector_type(4)));
typedef float   f32x4    __attribute__((ext_vector_type(4)));
typedef __bf16  bf16x8   __attribute__((ext_vector_type(8)));
typedef unsigned short ushort8v __attribute__((ext_vector_type(8)));
typedef unsigned short ushort2v __attribute__((ext_vector_type(2)));
typedef int     int4v    __attribute__((ext_vector_type(4)));

union frag_u { ushort8v u; bf16x8 b; };

__device__ __forceinline__ float us2f(unsigned short u) {
    union { unsigned int i; float f; } x; x.i = ((unsigned)u) << 16; return x.f;
}
__device__ __forceinline__ unsigned short f2us(float f) {
    union { __bf16 b; unsigned short u; } x; x.b = (__bf16)f; return x.u;
}
__device__ __forceinline__ float lrelu02(float x) { return x > 0.f ? x : 0.2f * x; }

// ---------------------------------------------------------------------------
// prep: blocks 0..255 -> Wgt; 256..511 -> Wcat; 512.. -> zero cnt+cursor
// ---------------------------------------------------------------------------
__global__ __launch_bounds__(256) void prep_misc(
    const float* __restrict__ Wg, const float* __restrict__ Wl,
    const float* __restrict__ Wr, unsigned short* __restrict__ Wgt,
    unsigned short* __restrict__ Wcat, int* __restrict__ zerop, int nz4)
{
    const int b = blockIdx.x, t = threadIdx.x;
    if (b < 256) {
        Wgt[b * 256 + t] = f2us(Wg[t * 256 + b]);
    } else if (b < 512) {
        const int n = b - 256;
        Wcat[n * 512 + t]       = f2us(Wl[t * 256 + n]);
        Wcat[n * 512 + 256 + t] = f2us(Wr[t * 256 + n]);
    } else {
        const int i = (b - 512) * 256 + t;
        if (i < nz4) ((int4v*)zerop)[i] = (int4v){0, 0, 0, 0};
    }
}

// ---------------------------------------------------------------------------
// bf16 MFMA GEMM: C[M,256] = A[M,K] @ Bt[256,K]^T
// Block: 512 thr (8 waves, 2x4), tile 128x256, BK=32 (padded LDS stride 40).
// Double-buffered LDS + register prefetch: 1 barrier per K-step.
// EPI=0: write bf16 (h+bg) + fused al_s/al_d dot-products (pre-bias).
//        COUNT: blocks >= nblk do edge_count for the CSR build instead.
// EPI=1: +bias, row-L2-normalize, write f32 out (rows guarded by M).
// AF32:  A is f32, converted to bf16 during staging (x is read only once).
// ---------------------------------------------------------------------------
template <int EPI, bool AF32, bool COUNT>
__global__ __launch_bounds__(512) void gemm_mfma(
    const void* __restrict__ Av, const unsigned short* __restrict__ Bt,
    int M, int K,
    unsigned short* __restrict__ hb_out,
    const float* __restrict__ avs, const float* __restrict__ avd,
    float* __restrict__ al_s, float* __restrict__ al_d,
    const float* __restrict__ bias, float* __restrict__ outp,
    int nblk, const int* __restrict__ dstE, int* __restrict__ cnt, int E)
{
    __shared__ __align__(16) unsigned short Als[2][128][40];
    __shared__ __align__(16) unsigned short Bls[2][256][40];
    __shared__ float red0[128];
    __shared__ float red1[128];

    if (COUNT && (int)blockIdx.x >= nblk) {
        const int i = ((int)blockIdx.x - nblk) * 512 + (int)threadIdx.x;
        if (i < E) atomicAdd(&cnt[dstE[i]], 1);
        return;
    }

    const int tid  = threadIdx.x;
    const int lane = tid & 63;
    const int wid  = tid >> 6;
    const int wr   = wid >> 2;      // 0..1
    const int wc   = wid & 3;       // 0..3
    const int row0 = blockIdx.x * 128;
    const int lg   = lane >> 4;     // 0..3
    const int lm   = lane & 15;

    f32x4 acc[4][4] = {};

    const int arow = tid >> 2;          // 0..127
    const int akof = (tid & 3) * 8;     // 0,8,16,24
    const int brow = tid >> 1;          // 0..255
    const int bkof = (tid & 1) * 16;    // 0,16
    const int nk   = K >> 5;

    ushort8v avr, bvr0, bvr1;

    auto load_t = [&](int kt) {
        const int k0 = kt * 32;
        if constexpr (AF32) {
            const float* ag = (const float*)Av + (size_t)(row0 + arow) * K + k0 + akof;
            const float4v v0 = *(const float4v*)ag;
            const float4v v1 = *(const float4v*)(ag + 4);
            avr[0]=f2us(v0[0]); avr[1]=f2us(v0[1]); avr[2]=f2us(v0[2]); avr[3]=f2us(v0[3]);
            avr[4]=f2us(v1[0]); avr[5]=f2us(v1[1]); avr[6]=f2us(v1[2]); avr[7]=f2us(v1[3]);
        } else {
            if (row0 + arow < M) {
                avr = *(const ushort8v*)((const unsigned short*)Av + (size_t)(row0 + arow) * K + k0 + akof);
            } else {
                avr = (ushort8v){0,0,0,0,0,0,0,0};
            }
        }
        const unsigned short* bgp = Bt + (size_t)brow * K + k0 + bkof;
        bvr0 = *(const ushort8v*)bgp;
        bvr1 = *(const ushort8v*)(bgp + 8);
    };
    auto store_t = [&](int b) {
        *(ushort8v*)&Als[b][arow][akof]     = avr;
        *(ushort8v*)&Bls[b][brow][bkof]     = bvr0;
        *(ushort8v*)&Bls[b][brow][bkof + 8] = bvr1;
    };

    load_t(0); store_t(0); __syncthreads();
    if (nk > 1) load_t(1);
    int cur = 0;

    for (int kt = 0; kt < nk; ++kt) {
        frag_u af[4], bf[4];
#pragma unroll
        for (int m = 0; m < 4; ++m)
            af[m].u = *(const ushort8v*)&Als[cur][wr*64 + m*16 + lm][lg*8];
#pragma unroll
        for (int n = 0; n < 4; ++n)
            bf[n].u = *(const ushort8v*)&Bls[cur][wc*64 + n*16 + lm][lg*8];
#pragma unroll
        for (int m = 0; m < 4; ++m)
#pragma unroll
            for (int n = 0; n < 4; ++n)
                acc[m][n] = __builtin_amdgcn_mfma_f32_16x16x32_bf16(
                    af[m].b, bf[n].b, acc[m][n], 0, 0, 0);
        if (kt + 1 < nk) {
            store_t(cur ^ 1);            // regs hold tile kt+1
            __syncthreads();
            if (kt + 2 < nk) load_t(kt + 2);
            cur ^= 1;
        }
    }

    if constexpr (EPI == 0) {
        if (tid < 128) { red0[tid] = 0.f; red1[tid] = 0.f; }
        __syncthreads();
        float asv[4], adv[4], bgv[4];
#pragma unroll
        for (int n = 0; n < 4; ++n) {
            const int col = wc*64 + n*16 + lm;
            asv[n] = avs[col]; adv[n] = avd[col]; bgv[n] = bias[col];
        }
#pragma unroll
        for (int m = 0; m < 4; ++m) {
#pragma unroll
            for (int j = 0; j < 4; ++j) {
                const int lr = wr*64 + m*16 + lg*4 + j;
                float ps = 0.f, pd = 0.f;
#pragma unroll
                for (int n = 0; n < 4; ++n) {
                    const float v = acc[m][n][j];
                    ps += v * asv[n]; pd += v * adv[n];
                    hb_out[(size_t)(row0 + lr) * 256 + wc*64 + n*16 + lm] = f2us(v + bgv[n]);
                }
#pragma unroll
                for (int off = 1; off < 16; off <<= 1) {
                    ps += __shfl_xor(ps, off);
                    pd += __shfl_xor(pd, off);
                }
                if (lm == 0) { atomicAdd(&red0[lr], ps); atomicAdd(&red1[lr], pd); }
            }
        }
        __syncthreads();
        if (tid < 128) { al_s[row0 + tid] = red0[tid]; al_d[row0 + tid] = red1[tid]; }
    } else {
        if (tid < 128) red0[tid] = 0.f;
        __syncthreads();
        float bv[4];
#pragma unroll
        for (int n = 0; n < 4; ++n) bv[n] = bias[wc*64 + n*16 + lm];
#pragma unroll
        for (int m = 0; m < 4; ++m) {
#pragma unroll
            for (int j = 0; j < 4; ++j) {
                const int lr = wr*64 + m*16 + lg*4 + j;
                float ss = 0.f;
#pragma unroll
                for (int n = 0; n < 4; ++n) {
                    const float v = acc[m][n][j] + bv[n];
                    acc[m][n][j] = v;
                    ss += v * v;
                }
#pragma unroll
                for (int off = 1; off < 16; off <<= 1) ss += __shfl_xor(ss, off);
                if (lm == 0) atomicAdd(&red0[lr], ss);
            }
        }
        __syncthreads();
#pragma unroll
        for (int m = 0; m < 4; ++m) {
#pragma unroll
            for (int j = 0; j < 4; ++j) {
                const int lr = wr*64 + m*16 + lg*4 + j;
                const int grow = row0 + lr;
                if (grow < M) {
                    const float inv = 1.0f / fmaxf(sqrtf(red0[lr]), 1e-12f);
#pragma unroll
                    for (int n = 0; n < 4; ++n)
                        outp[(size_t)grow * 256 + wc*64 + n*16 + lm] = acc[m][n][j] * inv;
                }
            }
        }
    }
}

// ---------------------------------------------------------------------------
// CSR: scan + scatter (scatter fused with src + edge softmax-weight w)
// ---------------------------------------------------------------------------
__global__ __launch_bounds__(1024) void scan_excl(
    const int* __restrict__ cnt, int* __restrict__ ptr, int n)
{
    __shared__ int part[1024];
    const int tid = threadIdx.x;
    const int chunk = (n + 1023) / 1024;
    const int i0 = tid * chunk;
    const int i1 = min(i0 + chunk, n);
    int s = 0;
    for (int i = i0; i < i1; ++i) s += cnt[i];
    part[tid] = s;
    __syncthreads();
    for (int off = 1; off < 1024; off <<= 1) {
        const int t = (tid >= off) ? part[tid - off] : 0;
        __syncthreads();
        part[tid] += t;
        __syncthreads();
    }
    int run = tid ? part[tid - 1] : 0;
    for (int i = i0; i < i1; ++i) { ptr[i] = run; run += cnt[i]; }
    if (tid == 1023) ptr[n] = part[1023];
}

__global__ void edge_scatter(const int* __restrict__ src, const int* __restrict__ dst,
                             const int* __restrict__ ptr, int* __restrict__ cursor,
                             const float* __restrict__ al_s, const float* __restrict__ al_d,
                             int* __restrict__ ssort, float* __restrict__ wbuf, int E)
{
    const int i = blockIdx.x * 256 + threadIdx.x;
    if (i < E) {
        const int d = dst[i];
        const int s = src[i];
        const int pos = ptr[d] + atomicAdd(&cursor[d], 1);
        ssort[pos] = s;
        wbuf[pos] = __expf(lrelu02(al_s[s] + al_d[d]));   // unshifted softmax wt
    }
}

// ---------------------------------------------------------------------------
// Fused GAT aggregation + SAGE partial sum over s>=ND neighbors.
// Block=128: 4 slots x 32 lanes; lane holds 8 channels. No stats pass:
// weights w are precomputed (edge_scatter); z = w_self + sum(w) is a cheap
// serial sum over the contiguous wbuf row, computed redundantly per thread.
// hb rows are loaded ONCE and feed both the gat-weighted sum and (if s>=ND)
// the plain sage sum. Writes h1a (bf16, bias included via hb=h+bg) into
// hcat[:,256:512] and the s>=ND partial sum (bf16) into hcat[:,0:256]
// (finished by sage_fin).
// ---------------------------------------------------------------------------
__global__ __launch_bounds__(128) void gat_sage(
    const unsigned short* __restrict__ hb, const float* __restrict__ al_s,
    const float* __restrict__ al_d, const int* __restrict__ ssort,
    const float* __restrict__ wbuf, const int* __restrict__ ptr,
    unsigned short* __restrict__ hcat)
{
    __shared__ float ldsg[4][264];
    __shared__ float ldss[4][264];
    const int v    = blockIdx.x;
    const int tid  = threadIdx.x;
    const int slot = tid >> 5;      // 0..3
    const int l32  = tid & 31;
    const int c0   = l32 * 8;
    const int p0 = ptr[v], p1 = ptr[v + 1];

    const float w_self = __expf(lrelu02(al_s[v] + al_d[v]));

    float accg[8], accs[8];
#pragma unroll
    for (int j = 0; j < 8; ++j) accs[j] = 0.f;
    if (slot == 0) {
        const ushort8v hv = *(const ushort8v*)&hb[(size_t)v * 256 + c0];
#pragma unroll
        for (int j = 0; j < 8; ++j) accg[j] = w_self * us2f(hv[j]);
    } else {
#pragma unroll
        for (int j = 0; j < 8; ++j) accg[j] = 0.f;
    }
    for (int p = p0 + slot; p < p1; p += 4) {
        const int s = ssort[p];
        const float w = wbuf[p];
        const ushort8v hv = *(const ushort8v*)&hb[(size_t)s * 256 + c0];
        const bool ge = (s >= ND);
#pragma unroll
        for (int j = 0; j < 8; ++j) {
            const float f = us2f(hv[j]);
            accg[j] = fmaf(w, f, accg[j]);
            accs[j] += ge ? f : 0.f;
        }
    }
    // z: cheap serial sum over contiguous weights (redundant per thread)
    float z = w_self;
    for (int p = p0; p < p1; ++p) z += wbuf[p];
    const float inv_z = 1.0f / z;

    *(f32x4*)&ldsg[slot][c0]     = (f32x4){accg[0], accg[1], accg[2], accg[3]};
    *(f32x4*)&ldsg[slot][c0 + 4] = (f32x4){accg[4], accg[5], accg[6], accg[7]};
    *(f32x4*)&ldss[slot][c0]     = (f32x4){accs[0], accs[1], accs[2], accs[3]};
    *(f32x4*)&ldss[slot][c0 + 4] = (f32x4){accs[4], accs[5], accs[6], accs[7]};
    __syncthreads();

    const int c = tid * 2;          // 2 channels per thread
    float rg0 = 0.f, rg1 = 0.f, rs0 = 0.f, rs1 = 0.f;
#pragma unroll
    for (int s2 = 0; s2 < 4; ++s2) {
        rg0 += ldsg[s2][c];     rg1 += ldsg[s2][c + 1];
        rs0 += ldss[s2][c];     rs1 += ldss[s2][c + 1];
    }
    *(ushort2v*)&hcat[(size_t)v * 512 + 256 + c] =
        (ushort2v){f2us(rg0 * inv_z), f2us(rg1 * inv_z)};
    *(ushort2v*)&hcat[(size_t)v * 512 + c] =
        (ushort2v){f2us(rs0), f2us(rs1)};               // psum (pre-mean)
}

// ---------------------------------------------------------------------------
// SAGE finisher: psum (bf16, in hcat[:,0:256]) += s<ND h1a gathers; divide by
// degree; write mean back in place. 4 dst per 256-thr block; each dst = 1
// wave = 2 slots x 32 lanes; cross-slot reduce via shfl_xor(32).
// ---------------------------------------------------------------------------
__global__ __launch_bounds__(256) void sage_fin(
    const int* __restrict__ ssort, const int* __restrict__ ptr,
    unsigned short* __restrict__ hcat)
{
    const int tid   = threadIdx.x;
    const int g     = tid >> 6;                 // 0..3 (one wave per dst)
    const int v     = blockIdx.x * 4 + g;
    const int slot2 = (tid >> 5) & 1;
    const int l32   = tid & 31;
    const int c0    = l32 * 8;
    const int p0 = ptr[v], p1 = ptr[v + 1];

    float acc[8];
    if (slot2 == 0) {
        const ushort8v pv = *(const ushort8v*)&hcat[(size_t)v * 512 + c0];
#pragma unroll
        for (int j = 0; j < 8; ++j) acc[j] = us2f(pv[j]);
    } else {
#pragma unroll
        for (int j = 0; j < 8; ++j) acc[j] = 0.f;
    }
    for (int p = p0 + slot2; p < p1; p += 2) {
        const int s = ssort[p];
        if (s < ND) {
            const ushort8v hv = *(const ushort8v*)&hcat[(size_t)s * 512 + 256 + c0];
#pragma unroll
            for (int j = 0; j < 8; ++j) acc[j] += us2f(hv[j]);
        }
    }
#pragma unroll
    for (int j = 0; j < 8; ++j) acc[j] += __shfl_xor(acc[j], 32);

    const int deg = p1 - p0;
    const float inv = (deg > 0) ? 1.0f / (float)deg : 0.f;
    if (slot2 == 0) {
        ushort8v o;
#pragma unroll
        for (int j = 0; j < 8; ++j) o[j] = f2us(acc[j] * inv);
        *(ushort8v*)&hcat[(size_t)v * 512 + c0] = o;
    }
}

// ---------------------------------------------------------------------------
extern "C" void kernel_launch(void* const* d_in, const int* in_sizes, int n_in,
                              void* d_out, int out_size, void* d_ws, size_t ws_size,
                              hipStream_t stream)
{
    const float* x    = (const float*)d_in[0];
    const float* Wg   = (const float*)d_in[1];
    const float* asrc = (const float*)d_in[2];
    const float* adst = (const float*)d_in[3];
    const float* bg   = (const float*)d_in[4];
    const float* Wl1  = (const float*)d_in[8];
    const float* bl1  = (const float*)d_in[9];
    const float* Wr1  = (const float*)d_in[10];
    const int*   src1 = (const int*)d_in[13];
    const int*   dst1 = (const int*)d_in[14];
    const int E1 = in_sizes[13];

    // workspace (cnt+cursor adjacent so one zero pass covers both)
    char* w = (char*)d_ws;
    unsigned short* hb   = (unsigned short*)w; w += (size_t)NS * 256 * 2;   // 40.96 MB
    unsigned short* hcat = (unsigned short*)w; w += (size_t)ND * 512 * 2;   // 20.48 MB
    unsigned short* Wgt  = (unsigned short*)w; w += 256 * 256 * 2;
    unsigned short* Wcat = (unsigned short*)w; w += 256 * 512 * 2;
    float* al_s = (float*)w; w += (size_t)NS * 4;
    float* al_d = (float*)w; w += (size_t)NS * 4;
    int* cnt    = (int*)w;   w += (size_t)ND * 4;
    int* cursor = (int*)w;   w += (size_t)ND * 4;
    int* ptrv   = (int*)w;   w += (size_t)(ND + 4) * 4;
    int* ssort  = (int*)w;   w += (size_t)E1 * 4;
    float* wbuf = (float*)w; w += (size_t)E1 * 4;

    const dim3 b256(256), b512(512);
    const int nz4 = 2 * ND / 4;   // cnt+cursor in int4s

    prep_misc<<<dim3(512 + (nz4 + 255) / 256), b256, 0, stream>>>(
        Wg, Wl1, Wr1, Wgt, Wcat, cnt, nz4);

    // h = x @ Wg + bg (bf16) with fused pre-bias al_s/al_d; edge_count fused
    const int nblk0 = NS / 128;
    const int ncnt  = (E1 + 511) / 512;
    gemm_mfma<0, true, true><<<dim3(nblk0 + ncnt), b512, 0, stream>>>(
        x, Wgt, NS, 256, hb, asrc, adst, al_s, al_d, bg, nullptr,
        nblk0, dst1, cnt, E1);

    scan_excl   <<<dim3(1), dim3(1024), 0, stream>>>(cnt, ptrv, ND);
    edge_scatter<<<dim3((E1 + 255) / 256), b256, 0, stream>>>(
        src1, dst1, ptrv, cursor, al_s, al_d, ssort, wbuf, E1);

    // fused GAT aggregate + SAGE s>=ND partial sum (psum bf16 in-place)
    gat_sage<<<dim3(ND), dim3(128), 0, stream>>>(hb, al_s, al_d, ssort, wbuf,
                                                 ptrv, hcat);
    // SAGE finisher: s<ND h1a gathers + divide
    sage_fin<<<dim3(ND / 4), b256, 0, stream>>>(ssort, ptrv, hcat);

    // out = normalize([mean|h1a] @ [Wl1;Wr1] + bl1)
    gemm_mfma<1, false, false><<<dim3((ND + 127) / 128), b512, 0, stream>>>(
        hcat, Wcat, ND, 512, nullptr, nullptr, nullptr, nullptr, nullptr,
        bl1, (float*)d_out, 0, nullptr, nullptr, 0);
}

// Round 9
// 149.375 us; speedup vs baseline: 3.7100x; 1.0930x over previous
//
#include <hip/hip_runtime.h>

// H=256, N1=80000, N2=20000, E1=300000. Layer 0 of the reference is dead code.
// Pipeline: prep (zero cnt + weight transpose/cast) -> gemm0 h=x@Wg+bg (bf16
// MFMA, dbuf-pipelined, fused al_s/al_d epilogue; edge_count+rank fused as
// extra blocks) -> scan -> edge_scatter (atomic-free via rank; fused edge
// weight w=exp(lrelu(logit)); max-shift dropped: logits are O(8), exp safe in
// f32 and coef=w/z is exact-ratio-identical) -> fused GAT aggregate + SAGE
// partial-sum (s>=ND; z folded into gather loop, unroll-2 pipeline) ->
// SAGE finisher (unroll-2) -> fused [mean|h1a]@[Wl1;Wr1]+bias+rownorm.
// bg folding: softmax coefs sum to 1, so aggregating (h+bg) gives gat+bg
// directly, and sage's s>=ND term needs h+bg anyway.

#define NS 80000
#define ND 20000

typedef float   float4v  __attribute__((ext_vector_type(4)));
typedef float   f32x4    __attribute__((ext_vector_type(4)));
typedef __bf16  bf16x8   __attribute__((ext_vector_type(8)));
typedef unsigned short ushort8v __attribute__((ext_vector_type(8)));
typedef unsigned short ushort2v __attribute__((ext_vector_type(2)));
typedef int     int4v    __attribute__((ext_vector_type(4)));

union frag_u { ushort8v u; bf16x8 b; };

__device__ __forceinline__ float us2f(unsigned short u) {
    union { unsigned int i; float f; } x; x.i = ((unsigned)u) << 16; return x.f;
}
__device__ __forceinline__ unsigned short f2us(float f) {
    union { __bf16 b; unsigned short u; } x; x.b = (__bf16)f; return x.u;
}
__device__ __forceinline__ float lrelu02(float x) { return x > 0.f ? x : 0.2f * x; }

// ---------------------------------------------------------------------------
// prep: blocks 0..255 -> Wgt; 256..511 -> Wcat; 512.. -> zero cnt
// ---------------------------------------------------------------------------
__global__ __launch_bounds__(256) void prep_misc(
    const float* __restrict__ Wg, const float* __restrict__ Wl,
    const float* __restrict__ Wr, unsigned short* __restrict__ Wgt,
    unsigned short* __restrict__ Wcat, int* __restrict__ zerop, int nz4)
{
    const int b = blockIdx.x, t = threadIdx.x;
    if (b < 256) {
        Wgt[b * 256 + t] = f2us(Wg[t * 256 + b]);
    } else if (b < 512) {
        const int n = b - 256;
        Wcat[n * 512 + t]       = f2us(Wl[t * 256 + n]);
        Wcat[n * 512 + 256 + t] = f2us(Wr[t * 256 + n]);
    } else {
        const int i = (b - 512) * 256 + t;
        if (i < nz4) ((int4v*)zerop)[i] = (int4v){0, 0, 0, 0};
    }
}

// ---------------------------------------------------------------------------
// bf16 MFMA GEMM: C[M,256] = A[M,K] @ Bt[256,K]^T
// Block: 512 thr (8 waves, 2x4), tile 128x256, BK=32 (padded LDS stride 40).
// Double-buffered LDS + register prefetch: 1 barrier per K-step.
// EPI=0: write bf16 (h+bg) + fused al_s/al_d dot-products (pre-bias).
//        COUNT: blocks >= nblk do edge_count + rank assignment instead.
// EPI=1: +bias, row-L2-normalize, write f32 out (rows guarded by M).
// AF32:  A is f32, converted to bf16 during staging (x is read only once).
// ---------------------------------------------------------------------------
template <int EPI, bool AF32, bool COUNT>
__global__ __launch_bounds__(512) void gemm_mfma(
    const void* __restrict__ Av, const unsigned short* __restrict__ Bt,
    int M, int K,
    unsigned short* __restrict__ hb_out,
    const float* __restrict__ avs, const float* __restrict__ avd,
    float* __restrict__ al_s, float* __restrict__ al_d,
    const float* __restrict__ bias, float* __restrict__ outp,
    int nblk, const int* __restrict__ dstE, int* __restrict__ cnt,
    int* __restrict__ rank, int E)
{
    __shared__ __align__(16) unsigned short Als[2][128][40];
    __shared__ __align__(16) unsigned short Bls[2][256][40];
    __shared__ float red0[128];
    __shared__ float red1[128];

    if (COUNT && (int)blockIdx.x >= nblk) {
        const int i = ((int)blockIdx.x - nblk) * 512 + (int)threadIdx.x;
        if (i < E) rank[i] = atomicAdd(&cnt[dstE[i]], 1);
        return;
    }

    const int tid  = threadIdx.x;
    const int lane = tid & 63;
    const int wid  = tid >> 6;
    const int wr   = wid >> 2;      // 0..1
    const int wc   = wid & 3;       // 0..3
    const int row0 = blockIdx.x * 128;
    const int lg   = lane >> 4;     // 0..3
    const int lm   = lane & 15;

    f32x4 acc[4][4] = {};

    const int arow = tid >> 2;          // 0..127
    const int akof = (tid & 3) * 8;     // 0,8,16,24
    const int brow = tid >> 1;          // 0..255
    const int bkof = (tid & 1) * 16;    // 0,16
    const int nk   = K >> 5;

    ushort8v avr, bvr0, bvr1;

    auto load_t = [&](int kt) {
        const int k0 = kt * 32;
        if constexpr (AF32) {
            const float* ag = (const float*)Av + (size_t)(row0 + arow) * K + k0 + akof;
            const float4v v0 = *(const float4v*)ag;
            const float4v v1 = *(const float4v*)(ag + 4);
            avr[0]=f2us(v0[0]); avr[1]=f2us(v0[1]); avr[2]=f2us(v0[2]); avr[3]=f2us(v0[3]);
            avr[4]=f2us(v1[0]); avr[5]=f2us(v1[1]); avr[6]=f2us(v1[2]); avr[7]=f2us(v1[3]);
        } else {
            if (row0 + arow < M) {
                avr = *(const ushort8v*)((const unsigned short*)Av + (size_t)(row0 + arow) * K + k0 + akof);
            } else {
                avr = (ushort8v){0,0,0,0,0,0,0,0};
            }
        }
        const unsigned short* bgp = Bt + (size_t)brow * K + k0 + bkof;
        bvr0 = *(const ushort8v*)bgp;
        bvr1 = *(const ushort8v*)(bgp + 8);
    };
    auto store_t = [&](int b) {
        *(ushort8v*)&Als[b][arow][akof]     = avr;
        *(ushort8v*)&Bls[b][brow][bkof]     = bvr0;
        *(ushort8v*)&Bls[b][brow][bkof + 8] = bvr1;
    };

    load_t(0); store_t(0); __syncthreads();
    if (nk > 1) load_t(1);
    int cur = 0;

    for (int kt = 0; kt < nk; ++kt) {
        frag_u af[4], bf[4];
#pragma unroll
        for (int m = 0; m < 4; ++m)
            af[m].u = *(const ushort8v*)&Als[cur][wr*64 + m*16 + lm][lg*8];
#pragma unroll
        for (int n = 0; n < 4; ++n)
            bf[n].u = *(const ushort8v*)&Bls[cur][wc*64 + n*16 + lm][lg*8];
#pragma unroll
        for (int m = 0; m < 4; ++m)
#pragma unroll
            for (int n = 0; n < 4; ++n)
                acc[m][n] = __builtin_amdgcn_mfma_f32_16x16x32_bf16(
                    af[m].b, bf[n].b, acc[m][n], 0, 0, 0);
        if (kt + 1 < nk) {
            store_t(cur ^ 1);            // regs hold tile kt+1
            __syncthreads();
            if (kt + 2 < nk) load_t(kt + 2);
            cur ^= 1;
        }
    }

    if constexpr (EPI == 0) {
        if (tid < 128) { red0[tid] = 0.f; red1[tid] = 0.f; }
        __syncthreads();
        float asv[4], adv[4], bgv[4];
#pragma unroll
        for (int n = 0; n < 4; ++n) {
            const int col = wc*64 + n*16 + lm;
            asv[n] = avs[col]; adv[n] = avd[col]; bgv[n] = bias[col];
        }
#pragma unroll
        for (int m = 0; m < 4; ++m) {
#pragma unroll
            for (int j = 0; j < 4; ++j) {
                const int lr = wr*64 + m*16 + lg*4 + j;
                float ps = 0.f, pd = 0.f;
#pragma unroll
                for (int n = 0; n < 4; ++n) {
                    const float v = acc[m][n][j];
                    ps += v * asv[n]; pd += v * adv[n];
                    hb_out[(size_t)(row0 + lr) * 256 + wc*64 + n*16 + lm] = f2us(v + bgv[n]);
                }
#pragma unroll
                for (int off = 1; off < 16; off <<= 1) {
                    ps += __shfl_xor(ps, off);
                    pd += __shfl_xor(pd, off);
                }
                if (lm == 0) { atomicAdd(&red0[lr], ps); atomicAdd(&red1[lr], pd); }
            }
        }
        __syncthreads();
        if (tid < 128) { al_s[row0 + tid] = red0[tid]; al_d[row0 + tid] = red1[tid]; }
    } else {
        if (tid < 128) red0[tid] = 0.f;
        __syncthreads();
        float bv[4];
#pragma unroll
        for (int n = 0; n < 4; ++n) bv[n] = bias[wc*64 + n*16 + lm];
#pragma unroll
        for (int m = 0; m < 4; ++m) {
#pragma unroll
            for (int j = 0; j < 4; ++j) {
                const int lr = wr*64 + m*16 + lg*4 + j;
                float ss = 0.f;
#pragma unroll
                for (int n = 0; n < 4; ++n) {
                    const float v = acc[m][n][j] + bv[n];
                    acc[m][n][j] = v;
                    ss += v * v;
                }
#pragma unroll
                for (int off = 1; off < 16; off <<= 1) ss += __shfl_xor(ss, off);
                if (lm == 0) atomicAdd(&red0[lr], ss);
            }
        }
        __syncthreads();
#pragma unroll
        for (int m = 0; m < 4; ++m) {
#pragma unroll
            for (int j = 0; j < 4; ++j) {
                const int lr = wr*64 + m*16 + lg*4 + j;
                const int grow = row0 + lr;
                if (grow < M) {
                    const float inv = 1.0f / fmaxf(sqrtf(red0[lr]), 1e-12f);
#pragma unroll
                    for (int n = 0; n < 4; ++n)
                        outp[(size_t)grow * 256 + wc*64 + n*16 + lm] = acc[m][n][j] * inv;
                }
            }
        }
    }
}

// ---------------------------------------------------------------------------
// CSR: scan + scatter (atomic-free via rank; fused softmax weight w)
// ---------------------------------------------------------------------------
__global__ __launch_bounds__(1024) void scan_excl(
    const int* __restrict__ cnt, int* __restrict__ ptr, int n)
{
    __shared__ int part[1024];
    const int tid = threadIdx.x;
    const int chunk = (n + 1023) / 1024;
    const int i0 = tid * chunk;
    const int i1 = min(i0 + chunk, n);
    int s = 0;
    for (int i = i0; i < i1; ++i) s += cnt[i];
    part[tid] = s;
    __syncthreads();
    for (int off = 1; off < 1024; off <<= 1) {
        const int t = (tid >= off) ? part[tid - off] : 0;
        __syncthreads();
        part[tid] += t;
        __syncthreads();
    }
    int run = tid ? part[tid - 1] : 0;
    for (int i = i0; i < i1; ++i) { ptr[i] = run; run += cnt[i]; }
    if (tid == 1023) ptr[n] = part[1023];
}

__global__ void edge_scatter(const int* __restrict__ src, const int* __restrict__ dst,
                             const int* __restrict__ ptr, const int* __restrict__ rank,
                             const float* __restrict__ al_s, const float* __restrict__ al_d,
                             int* __restrict__ ssort, float* __restrict__ wbuf, int E)
{
    const int i = blockIdx.x * 256 + threadIdx.x;
    if (i < E) {
        const int d = dst[i];
        const int s = src[i];
        const int pos = ptr[d] + rank[i];
        ssort[pos] = s;
        wbuf[pos] = __expf(lrelu02(al_s[s] + al_d[d]));   // unshifted softmax wt
    }
}

// ---------------------------------------------------------------------------
// Fused GAT aggregation + SAGE partial sum over s>=ND neighbors.
// Block=128: 4 slots x 32 lanes; lane holds 8 channels. Weights w are
// precomputed (edge_scatter). z-partials are folded into the gather loop
// (all lanes of a slot read the same wbuf[p] -> broadcast) and reduced via
// zp[4] across the existing barrier. Gather loop is unrolled by 2 with both
// row loads issued up front (2 loads in flight per thread).
// Writes h1a (bf16, bias included via hb=h+bg) into hcat[:,256:512] and the
// s>=ND partial sum (bf16) into hcat[:,0:256] (finished by sage_fin).
// ---------------------------------------------------------------------------
__global__ __launch_bounds__(128) void gat_sage(
    const unsigned short* __restrict__ hb, const float* __restrict__ al_s,
    const float* __restrict__ al_d, const int* __restrict__ ssort,
    const float* __restrict__ wbuf, const int* __restrict__ ptr,
    unsigned short* __restrict__ hcat)
{
    __shared__ float ldsg[4][264];
    __shared__ float ldss[4][264];
    __shared__ float zp[4];
    const int v    = blockIdx.x;
    const int tid  = threadIdx.x;
    const int slot = tid >> 5;      // 0..3
    const int l32  = tid & 31;
    const int c0   = l32 * 8;
    const int p0 = ptr[v], p1 = ptr[v + 1];

    const float w_self = __expf(lrelu02(al_s[v] + al_d[v]));

    float accg[8], accs[8];
    float zpart = 0.f;
#pragma unroll
    for (int j = 0; j < 8; ++j) accs[j] = 0.f;
    if (slot == 0) {
        const ushort8v hv = *(const ushort8v*)&hb[(size_t)v * 256 + c0];
#pragma unroll
        for (int j = 0; j < 8; ++j) accg[j] = w_self * us2f(hv[j]);
    } else {
#pragma unroll
        for (int j = 0; j < 8; ++j) accg[j] = 0.f;
    }

    int p = p0 + slot;
    for (; p + 4 < p1; p += 8) {            // 2 edges per iteration
        const int s0 = ssort[p];
        const int s1 = ssort[p + 4];
        const float w0 = wbuf[p];
        const float w1 = wbuf[p + 4];
        const ushort8v h0 = *(const ushort8v*)&hb[(size_t)s0 * 256 + c0];
        const ushort8v h1 = *(const ushort8v*)&hb[(size_t)s1 * 256 + c0];
        zpart += w0 + w1;
        const bool g0 = (s0 >= ND), g1 = (s1 >= ND);
#pragma unroll
        for (int j = 0; j < 8; ++j) {
            const float f0 = us2f(h0[j]);
            const float f1 = us2f(h1[j]);
            accg[j] = fmaf(w0, f0, accg[j]);
            accg[j] = fmaf(w1, f1, accg[j]);
            accs[j] += (g0 ? f0 : 0.f) + (g1 ? f1 : 0.f);
        }
    }
    if (p < p1) {                           // tail edge
        const int s0 = ssort[p];
        const float w0 = wbuf[p];
        const ushort8v h0 = *(const ushort8v*)&hb[(size_t)s0 * 256 + c0];
        zpart += w0;
        const bool g0 = (s0 >= ND);
#pragma unroll
        for (int j = 0; j < 8; ++j) {
            const float f0 = us2f(h0[j]);
            accg[j] = fmaf(w0, f0, accg[j]);
            accs[j] += g0 ? f0 : 0.f;
        }
    }

    if (l32 == 0) zp[slot] = zpart;
    *(f32x4*)&ldsg[slot][c0]     = (f32x4){accg[0], accg[1], accg[2], accg[3]};
    *(f32x4*)&ldsg[slot][c0 + 4] = (f32x4){accg[4], accg[5], accg[6], accg[7]};
    *(f32x4*)&ldss[slot][c0]     = (f32x4){accs[0], accs[1], accs[2], accs[3]};
    *(f32x4*)&ldss[slot][c0 + 4] = (f32x4){accs[4], accs[5], accs[6], accs[7]};
    __syncthreads();

    const float inv_z = 1.0f / (w_self + zp[0] + zp[1] + zp[2] + zp[3]);
    const int c = tid * 2;          // 2 channels per thread
    float rg0 = 0.f, rg1 = 0.f, rs0 = 0.f, rs1 = 0.f;
#pragma unroll
    for (int s2 = 0; s2 < 4; ++s2) {
        rg0 += ldsg[s2][c];     rg1 += ldsg[s2][c + 1];
        rs0 += ldss[s2][c];     rs1 += ldss[s2][c + 1];
    }
    *(ushort2v*)&hcat[(size_t)v * 512 + 256 + c] =
        (ushort2v){f2us(rg0 * inv_z), f2us(rg1 * inv_z)};
    *(ushort2v*)&hcat[(size_t)v * 512 + c] =
        (ushort2v){f2us(rs0), f2us(rs1)};               // psum (pre-mean)
}

// ---------------------------------------------------------------------------
// SAGE finisher: psum (bf16, in hcat[:,0:256]) += s<ND h1a gathers; divide by
// degree; write mean back in place. 4 dst per 256-thr block; each dst = 1
// wave = 2 slots x 32 lanes; unroll-2; cross-slot reduce via shfl_xor(32).
// ---------------------------------------------------------------------------
__global__ __launch_bounds__(256) void sage_fin(
    const int* __restrict__ ssort, const int* __restrict__ ptr,
    unsigned short* __restrict__ hcat)
{
    const int tid   = threadIdx.x;
    const int g     = tid >> 6;                 // 0..3 (one wave per dst)
    const int v     = blockIdx.x * 4 + g;
    const int slot2 = (tid >> 5) & 1;
    const int l32   = tid & 31;
    const int c0    = l32 * 8;
    const int p0 = ptr[v], p1 = ptr[v + 1];

    float acc[8];
    if (slot2 == 0) {
        const ushort8v pv = *(const ushort8v*)&hcat[(size_t)v * 512 + c0];
#pragma unroll
        for (int j = 0; j < 8; ++j) acc[j] = us2f(pv[j]);
    } else {
#pragma unroll
        for (int j = 0; j < 8; ++j) acc[j] = 0.f;
    }
    int p = p0 + slot2;
    for (; p + 2 < p1; p += 4) {                // 2 edges per iteration
        const int s0 = ssort[p];
        const int s1 = ssort[p + 2];
        if (s0 < ND) {
            const ushort8v hv = *(const ushort8v*)&hcat[(size_t)s0 * 512 + 256 + c0];
#pragma unroll
            for (int j = 0; j < 8; ++j) acc[j] += us2f(hv[j]);
        }
        if (s1 < ND) {
            const ushort8v hv = *(const ushort8v*)&hcat[(size_t)s1 * 512 + 256 + c0];
#pragma unroll
            for (int j = 0; j < 8; ++j) acc[j] += us2f(hv[j]);
        }
    }
    if (p < p1) {
        const int s0 = ssort[p];
        if (s0 < ND) {
            const ushort8v hv = *(const ushort8v*)&hcat[(size_t)s0 * 512 + 256 + c0];
#pragma unroll
            for (int j = 0; j < 8; ++j) acc[j] += us2f(hv[j]);
        }
    }
#pragma unroll
    for (int j = 0; j < 8; ++j) acc[j] += __shfl_xor(acc[j], 32);

    const int deg = p1 - p0;
    const float inv = (deg > 0) ? 1.0f / (float)deg : 0.f;
    if (slot2 == 0) {
        ushort8v o;
#pragma unroll
        for (int j = 0; j < 8; ++j) o[j] = f2us(acc[j] * inv);
        *(ushort8v*)&hcat[(size_t)v * 512 + c0] = o;
    }
}

// ---------------------------------------------------------------------------
extern "C" void kernel_launch(void* const* d_in, const int* in_sizes, int n_in,
                              void* d_out, int out_size, void* d_ws, size_t ws_size,
                              hipStream_t stream)
{
    const float* x    = (const float*)d_in[0];
    const float* Wg   = (const float*)d_in[1];
    const float* asrc = (const float*)d_in[2];
    const float* adst = (const float*)d_in[3];
    const float* bg   = (const float*)d_in[4];
    const float* Wl1  = (const float*)d_in[8];
    const float* bl1  = (const float*)d_in[9];
    const float* Wr1  = (const float*)d_in[10];
    const int*   src1 = (const int*)d_in[13];
    const int*   dst1 = (const int*)d_in[14];
    const int E1 = in_sizes[13];

    // workspace
    char* w = (char*)d_ws;
    unsigned short* hb   = (unsigned short*)w; w += (size_t)NS * 256 * 2;   // 40.96 MB
    unsigned short* hcat = (unsigned short*)w; w += (size_t)ND * 512 * 2;   // 20.48 MB
    unsigned short* Wgt  = (unsigned short*)w; w += 256 * 256 * 2;
    unsigned short* Wcat = (unsigned short*)w; w += 256 * 512 * 2;
    float* al_s = (float*)w; w += (size_t)NS * 4;
    float* al_d = (float*)w; w += (size_t)NS * 4;
    int* cnt    = (int*)w;   w += (size_t)ND * 4;
    int* ptrv   = (int*)w;   w += (size_t)(ND + 4) * 4;
    int* rank   = (int*)w;   w += (size_t)E1 * 4;
    int* ssort  = (int*)w;   w += (size_t)E1 * 4;
    float* wbuf = (float*)w; w += (size_t)E1 * 4;

    const dim3 b256(256), b512(512);
    const int nz4 = ND / 4;   // cnt in int4s

    prep_misc<<<dim3(512 + (nz4 + 255) / 256), b256, 0, stream>>>(
        Wg, Wl1, Wr1, Wgt, Wcat, cnt, nz4);

    // h = x @ Wg + bg (bf16) with fused pre-bias al_s/al_d; count+rank fused
    const int nblk0 = NS / 128;
    const int ncnt  = (E1 + 511) / 512;
    gemm_mfma<0, true, true><<<dim3(nblk0 + ncnt), b512, 0, stream>>>(
        x, Wgt, NS, 256, hb, asrc, adst, al_s, al_d, bg, nullptr,
        nblk0, dst1, cnt, rank, E1);

    scan_excl   <<<dim3(1), dim3(1024), 0, stream>>>(cnt, ptrv, ND);
    edge_scatter<<<dim3((E1 + 255) / 256), b256, 0, stream>>>(
        src1, dst1, ptrv, rank, al_s, al_d, ssort, wbuf, E1);

    // fused GAT aggregate + SAGE s>=ND partial sum (psum bf16 in-place)
    gat_sage<<<dim3(ND), dim3(128), 0, stream>>>(hb, al_s, al_d, ssort, wbuf,
                                                 ptrv, hcat);
    // SAGE finisher: s<ND h1a gathers + divide
    sage_fin<<<dim3(ND / 4), b256, 0, stream>>>(ssort, ptrv, hcat);

    // out = normalize([mean|h1a] @ [Wl1;Wr1] + bl1)
    gemm_mfma<1, false, false><<<dim3((ND + 127) / 128), b512, 0, stream>>>(
        hcat, Wcat, ND, 512, nullptr, nullptr, nullptr, nullptr, nullptr,
        bl1, (float*)d_out, 0, nullptr, nullptr, nullptr, 0);
}

// Round 10
// 144.498 us; speedup vs baseline: 3.8352x; 1.0337x over previous
//
#include <hip/hip_runtime.h>

// H=256, N1=80000, N2=20000, E1=300000. Layer 0 of the reference is dead code.
// Pipeline: prep (zero cntpair + weight transpose/cast) -> count_rank
// (class-aware per-dst pair counters; rank within class) -> gemm0 h=x@Wg+bg
// (bf16 MFMA, dbuf-pipelined, fused al_s/al_d epilogue; CSR scan fused as one
// extra block) -> edge_scatter (atomic-free, class-ordered: s<ND edges first
// in each row) -> gat_sage (w=exp(lrelu()) inline; z folded into gather loop;
// unroll-2) -> sage_fin (lt-edges only, no branch) ->
// gemm1 [mean|h1a]@[Wl1;Wr1]+bias+rownorm.
// bg folding: softmax coefs sum to 1, so aggregating (h+bg) gives gat+bg
// directly, and sage's s>=ND term needs h+bg anyway. Max-shift dropped:
// logits are O(8), exp safe in f32, coef=w/z is exact-ratio-identical.

#define NS 80000
#define ND 20000

typedef float   float4v  __attribute__((ext_vector_type(4)));
typedef float   f32x4    __attribute__((ext_vector_type(4)));
typedef __bf16  bf16x8   __attribute__((ext_vector_type(8)));
typedef unsigned short ushort8v __attribute__((ext_vector_type(8)));
typedef unsigned short ushort2v __attribute__((ext_vector_type(2)));
typedef int     int4v    __attribute__((ext_vector_type(4)));

union frag_u { ushort8v u; bf16x8 b; };

__device__ __forceinline__ float us2f(unsigned short u) {
    union { unsigned int i; float f; } x; x.i = ((unsigned)u) << 16; return x.f;
}
__device__ __forceinline__ unsigned short f2us(float f) {
    union { __bf16 b; unsigned short u; } x; x.b = (__bf16)f; return x.u;
}
__device__ __forceinline__ float lrelu02(float x) { return x > 0.f ? x : 0.2f * x; }

// ---------------------------------------------------------------------------
// prep: blocks 0..255 -> Wgt; 256..511 -> Wcat; 512.. -> zero cntpair
// ---------------------------------------------------------------------------
__global__ __launch_bounds__(256) void prep_misc(
    const float* __restrict__ Wg, const float* __restrict__ Wl,
    const float* __restrict__ Wr, unsigned short* __restrict__ Wgt,
    unsigned short* __restrict__ Wcat, int* __restrict__ zerop, int nz4)
{
    const int b = blockIdx.x, t = threadIdx.x;
    if (b < 256) {
        Wgt[b * 256 + t] = f2us(Wg[t * 256 + b]);
    } else if (b < 512) {
        const int n = b - 256;
        Wcat[n * 512 + t]       = f2us(Wl[t * 256 + n]);
        Wcat[n * 512 + 256 + t] = f2us(Wr[t * 256 + n]);
    } else {
        const int i = (b - 512) * 256 + t;
        if (i < nz4) ((int4v*)zerop)[i] = (int4v){0, 0, 0, 0};
    }
}

// ---------------------------------------------------------------------------
// count + rank within class: cntpair[2d] = #edges with s<ND, cntpair[2d+1]
// the rest. rank[i] = arrival order within (d, class).
// ---------------------------------------------------------------------------
__global__ void count_rank(const int* __restrict__ src, const int* __restrict__ dst,
                           int* __restrict__ cntpair, int* __restrict__ rank, int E)
{
    const int i = blockIdx.x * 256 + threadIdx.x;
    if (i < E) {
        const int d = dst[i];
        const int cls = (src[i] < ND) ? 0 : 1;
        rank[i] = atomicAdd(&cntpair[2 * d + cls], 1);
    }
}

// ---------------------------------------------------------------------------
// bf16 MFMA GEMM: C[M,256] = A[M,K] @ Bt[256,K]^T
// Block: 512 thr (8 waves, 2x4), tile 128x256, BK=32 (padded LDS stride 40).
// Double-buffered LDS + register prefetch: 1 barrier per K-step.
// EPI=0: write bf16 (h+bg) + fused al_s/al_d dot-products (pre-bias).
//        SCAN: block nblk runs the CSR exclusive scan over cntpair instead.
// EPI=1: +bias, row-L2-normalize, write f32 out (rows guarded by M).
// AF32:  A is f32, converted to bf16 during staging (x is read only once).
// ---------------------------------------------------------------------------
template <int EPI, bool AF32, bool SCAN>
__global__ __launch_bounds__(512) void gemm_mfma(
    const void* __restrict__ Av, const unsigned short* __restrict__ Bt,
    int M, int K,
    unsigned short* __restrict__ hb_out,
    const float* __restrict__ avs, const float* __restrict__ avd,
    float* __restrict__ al_s, float* __restrict__ al_d,
    const float* __restrict__ bias, float* __restrict__ outp,
    int nblk, const int* __restrict__ cntpair, int* __restrict__ ptrp)
{
    __shared__ __align__(16) unsigned short Als[2][128][40];
    __shared__ __align__(16) unsigned short Bls[2][256][40];
    __shared__ float red0[128];
    __shared__ float red1[128];

    if (SCAN && (int)blockIdx.x >= nblk) {
        int* part = (int*)Als;               // reuse LDS (512 ints)
        const int tid = threadIdx.x;
        const int chunk = (ND + 511) / 512;
        const int i0 = tid * chunk;
        const int i1 = min(i0 + chunk, ND);
        int s = 0;
        for (int i = i0; i < i1; ++i) s += cntpair[2*i] + cntpair[2*i+1];
        part[tid] = s;
        __syncthreads();
        for (int off = 1; off < 512; off <<= 1) {
            const int t = (tid >= off) ? part[tid - off] : 0;
            __syncthreads();
            part[tid] += t;
            __syncthreads();
        }
        int run = tid ? part[tid - 1] : 0;
        for (int i = i0; i < i1; ++i) { ptrp[i] = run; run += cntpair[2*i] + cntpair[2*i+1]; }
        if (tid == 511) ptrp[ND] = part[511];
        return;
    }

    const int tid  = threadIdx.x;
    const int lane = tid & 63;
    const int wid  = tid >> 6;
    const int wr   = wid >> 2;      // 0..1
    const int wc   = wid & 3;       // 0..3
    const int row0 = blockIdx.x * 128;
    const int lg   = lane >> 4;     // 0..3
    const int lm   = lane & 15;

    f32x4 acc[4][4] = {};

    const int arow = tid >> 2;          // 0..127
    const int akof = (tid & 3) * 8;     // 0,8,16,24
    const int brow = tid >> 1;          // 0..255
    const int bkof = (tid & 1) * 16;    // 0,16
    const int nk   = K >> 5;

    ushort8v avr, bvr0, bvr1;

    auto load_t = [&](int kt) {
        const int k0 = kt * 32;
        if constexpr (AF32) {
            const float* ag = (const float*)Av + (size_t)(row0 + arow) * K + k0 + akof;
            const float4v v0 = *(const float4v*)ag;
            const float4v v1 = *(const float4v*)(ag + 4);
            avr[0]=f2us(v0[0]); avr[1]=f2us(v0[1]); avr[2]=f2us(v0[2]); avr[3]=f2us(v0[3]);
            avr[4]=f2us(v1[0]); avr[5]=f2us(v1[1]); avr[6]=f2us(v1[2]); avr[7]=f2us(v1[3]);
        } else {
            if (row0 + arow < M) {
                avr = *(const ushort8v*)((const unsigned short*)Av + (size_t)(row0 + arow) * K + k0 + akof);
            } else {
                avr = (ushort8v){0,0,0,0,0,0,0,0};
            }
        }
        const unsigned short* bgp = Bt + (size_t)brow * K + k0 + bkof;
        bvr0 = *(const ushort8v*)bgp;
        bvr1 = *(const ushort8v*)(bgp + 8);
    };
    auto store_t = [&](int b) {
        *(ushort8v*)&Als[b][arow][akof]     = avr;
        *(ushort8v*)&Bls[b][brow][bkof]     = bvr0;
        *(ushort8v*)&Bls[b][brow][bkof + 8] = bvr1;
    };

    load_t(0); store_t(0); __syncthreads();
    if (nk > 1) load_t(1);
    int cur = 0;

    for (int kt = 0; kt < nk; ++kt) {
        frag_u af[4], bf[4];
#pragma unroll
        for (int m = 0; m < 4; ++m)
            af[m].u = *(const ushort8v*)&Als[cur][wr*64 + m*16 + lm][lg*8];
#pragma unroll
        for (int n = 0; n < 4; ++n)
            bf[n].u = *(const ushort8v*)&Bls[cur][wc*64 + n*16 + lm][lg*8];
#pragma unroll
        for (int m = 0; m < 4; ++m)
#pragma unroll
            for (int n = 0; n < 4; ++n)
                acc[m][n] = __builtin_amdgcn_mfma_f32_16x16x32_bf16(
                    af[m].b, bf[n].b, acc[m][n], 0, 0, 0);
        if (kt + 1 < nk) {
            store_t(cur ^ 1);            // regs hold tile kt+1
            __syncthreads();
            if (kt + 2 < nk) load_t(kt + 2);
            cur ^= 1;
        }
    }

    if constexpr (EPI == 0) {
        if (tid < 128) { red0[tid] = 0.f; red1[tid] = 0.f; }
        __syncthreads();
        float asv[4], adv[4], bgv[4];
#pragma unroll
        for (int n = 0; n < 4; ++n) {
            const int col = wc*64 + n*16 + lm;
            asv[n] = avs[col]; adv[n] = avd[col]; bgv[n] = bias[col];
        }
#pragma unroll
        for (int m = 0; m < 4; ++m) {
#pragma unroll
            for (int j = 0; j < 4; ++j) {
                const int lr = wr*64 + m*16 + lg*4 + j;
                float ps = 0.f, pd = 0.f;
#pragma unroll
                for (int n = 0; n < 4; ++n) {
                    const float v = acc[m][n][j];
                    ps += v * asv[n]; pd += v * adv[n];
                    hb_out[(size_t)(row0 + lr) * 256 + wc*64 + n*16 + lm] = f2us(v + bgv[n]);
                }
#pragma unroll
                for (int off = 1; off < 16; off <<= 1) {
                    ps += __shfl_xor(ps, off);
                    pd += __shfl_xor(pd, off);
                }
                if (lm == 0) { atomicAdd(&red0[lr], ps); atomicAdd(&red1[lr], pd); }
            }
        }
        __syncthreads();
        if (tid < 128) { al_s[row0 + tid] = red0[tid]; al_d[row0 + tid] = red1[tid]; }
    } else {
        if (tid < 128) red0[tid] = 0.f;
        __syncthreads();
        float bv[4];
#pragma unroll
        for (int n = 0; n < 4; ++n) bv[n] = bias[wc*64 + n*16 + lm];
#pragma unroll
        for (int m = 0; m < 4; ++m) {
#pragma unroll
            for (int j = 0; j < 4; ++j) {
                const int lr = wr*64 + m*16 + lg*4 + j;
                float ss = 0.f;
#pragma unroll
                for (int n = 0; n < 4; ++n) {
                    const float v = acc[m][n][j] + bv[n];
                    acc[m][n][j] = v;
                    ss += v * v;
                }
#pragma unroll
                for (int off = 1; off < 16; off <<= 1) ss += __shfl_xor(ss, off);
                if (lm == 0) atomicAdd(&red0[lr], ss);
            }
        }
        __syncthreads();
#pragma unroll
        for (int m = 0; m < 4; ++m) {
#pragma unroll
            for (int j = 0; j < 4; ++j) {
                const int lr = wr*64 + m*16 + lg*4 + j;
                const int grow = row0 + lr;
                if (grow < M) {
                    const float inv = 1.0f / fmaxf(sqrtf(red0[lr]), 1e-12f);
#pragma unroll
                    for (int n = 0; n < 4; ++n)
                        outp[(size_t)grow * 256 + wc*64 + n*16 + lm] = acc[m][n][j] * inv;
                }
            }
        }
    }
}

// ---------------------------------------------------------------------------
// scatter: atomic-free via rank; class-ordered (s<ND first within each row)
// ---------------------------------------------------------------------------
__global__ void edge_scatter(const int* __restrict__ src, const int* __restrict__ dst,
                             const int* __restrict__ ptrp, const int* __restrict__ rank,
                             const int* __restrict__ cntpair,
                             int* __restrict__ ssort, int E)
{
    const int i = blockIdx.x * 256 + threadIdx.x;
    if (i < E) {
        const int d = dst[i];
        const int s = src[i];
        const int base = ptrp[d];
        const int pos = (s < ND) ? base + rank[i]
                                 : base + cntpair[2 * d] + rank[i];
        ssort[pos] = s;
    }
}

// ---------------------------------------------------------------------------
// Fused GAT aggregation + SAGE partial sum over s>=ND neighbors.
// Block=128: 4 slots x 32 lanes; lane holds 8 channels. Weight w computed
// inline: al_s[s] is an L2-resident broadcast read per edge. z-partials are
// folded into the gather loop and reduced via zp[4] across the barrier.
// Gather loop unrolled by 2 (2 row loads in flight per thread).
// Writes h1a (bf16, bias included via hb=h+bg) into hcat[:,256:512] and the
// s>=ND partial sum (bf16) into hcat[:,0:256] (finished by sage_fin).
// ---------------------------------------------------------------------------
__global__ __launch_bounds__(128) void gat_sage(
    const unsigned short* __restrict__ hb, const float* __restrict__ al_s,
    const float* __restrict__ al_d, const int* __restrict__ ssort,
    const int* __restrict__ ptrp, unsigned short* __restrict__ hcat)
{
    __shared__ float ldsg[4][264];
    __shared__ float ldss[4][264];
    __shared__ float zp[4];
    const int v    = blockIdx.x;
    const int tid  = threadIdx.x;
    const int slot = tid >> 5;      // 0..3
    const int l32  = tid & 31;
    const int c0   = l32 * 8;
    const int p0 = ptrp[v], p1 = ptrp[v + 1];

    const float ad     = al_d[v];
    const float w_self = __expf(lrelu02(al_s[v] + ad));

    float accg[8], accs[8];
    float zpart = 0.f;
#pragma unroll
    for (int j = 0; j < 8; ++j) accs[j] = 0.f;
    if (slot == 0) {
        const ushort8v hv = *(const ushort8v*)&hb[(size_t)v * 256 + c0];
#pragma unroll
        for (int j = 0; j < 8; ++j) accg[j] = w_self * us2f(hv[j]);
    } else {
#pragma unroll
        for (int j = 0; j < 8; ++j) accg[j] = 0.f;
    }

    int p = p0 + slot;
    for (; p + 4 < p1; p += 8) {            // 2 edges per iteration
        const int s0 = ssort[p];
        const int s1 = ssort[p + 4];
        const float w0 = __expf(lrelu02(al_s[s0] + ad));
        const float w1 = __expf(lrelu02(al_s[s1] + ad));
        const ushort8v h0 = *(const ushort8v*)&hb[(size_t)s0 * 256 + c0];
        const ushort8v h1 = *(const ushort8v*)&hb[(size_t)s1 * 256 + c0];
        zpart += w0 + w1;
        const bool g0 = (s0 >= ND), g1 = (s1 >= ND);
#pragma unroll
        for (int j = 0; j < 8; ++j) {
            const float f0 = us2f(h0[j]);
            const float f1 = us2f(h1[j]);
            accg[j] = fmaf(w0, f0, accg[j]);
            accg[j] = fmaf(w1, f1, accg[j]);
            accs[j] += (g0 ? f0 : 0.f) + (g1 ? f1 : 0.f);
        }
    }
    if (p < p1) {                           // tail edge
        const int s0 = ssort[p];
        const float w0 = __expf(lrelu02(al_s[s0] + ad));
        const ushort8v h0 = *(const ushort8v*)&hb[(size_t)s0 * 256 + c0];
        zpart += w0;
        const bool g0 = (s0 >= ND);
#pragma unroll
        for (int j = 0; j < 8; ++j) {
            const float f0 = us2f(h0[j]);
            accg[j] = fmaf(w0, f0, accg[j]);
            accs[j] += g0 ? f0 : 0.f;
        }
    }

    if (l32 == 0) zp[slot] = zpart;
    *(f32x4*)&ldsg[slot][c0]     = (f32x4){accg[0], accg[1], accg[2], accg[3]};
    *(f32x4*)&ldsg[slot][c0 + 4] = (f32x4){accg[4], accg[5], accg[6], accg[7]};
    *(f32x4*)&ldss[slot][c0]     = (f32x4){accs[0], accs[1], accs[2], accs[3]};
    *(f32x4*)&ldss[slot][c0 + 4] = (f32x4){accs[4], accs[5], accs[6], accs[7]};
    __syncthreads();

    const float inv_z = 1.0f / (w_self + zp[0] + zp[1] + zp[2] + zp[3]);
    const int c = tid * 2;          // 2 channels per thread
    float rg0 = 0.f, rg1 = 0.f, rs0 = 0.f, rs1 = 0.f;
#pragma unroll
    for (int s2 = 0; s2 < 4; ++s2) {
        rg0 += ldsg[s2][c];     rg1 += ldsg[s2][c + 1];
        rs0 += ldss[s2][c];     rs1 += ldss[s2][c + 1];
    }
    *(ushort2v*)&hcat[(size_t)v * 512 + 256 + c] =
        (ushort2v){f2us(rg0 * inv_z), f2us(rg1 * inv_z)};
    *(ushort2v*)&hcat[(size_t)v * 512 + c] =
        (ushort2v){f2us(rs0), f2us(rs1)};               // psum (pre-mean)
}

// ---------------------------------------------------------------------------
// SAGE finisher: psum (bf16, in hcat[:,0:256]) += s<ND h1a gathers (class-
// ordered CSR: only the first cntpair[2v] edges, no branch); divide by
// degree; write mean back in place. 4 dst per 256-thr block; each dst = 1
// wave = 2 slots x 32 lanes; unroll-2; cross-slot reduce via shfl_xor(32).
// ---------------------------------------------------------------------------
__global__ __launch_bounds__(256) void sage_fin(
    const int* __restrict__ ssort, const int* __restrict__ ptrp,
    const int* __restrict__ cntpair, unsigned short* __restrict__ hcat)
{
    const int tid   = threadIdx.x;
    const int g     = tid >> 6;                 // 0..3 (one wave per dst)
    const int v     = blockIdx.x * 4 + g;
    const int slot2 = (tid >> 5) & 1;
    const int l32   = tid & 31;
    const int c0    = l32 * 8;
    const int p0  = ptrp[v];
    const int p1l = p0 + cntpair[2 * v];        // lt-edges only
    const int deg = ptrp[v + 1] - p0;

    float acc[8];
    if (slot2 == 0) {
        const ushort8v pv = *(const ushort8v*)&hcat[(size_t)v * 512 + c0];
#pragma unroll
        for (int j = 0; j < 8; ++j) acc[j] = us2f(pv[j]);
    } else {
#pragma unroll
        for (int j = 0; j < 8; ++j) acc[j] = 0.f;
    }
    int p = p0 + slot2;
    for (; p + 2 < p1l; p += 4) {               // 2 edges per iteration
        const int s0 = ssort[p];
        const int s1 = ssort[p + 2];
        const ushort8v h0 = *(const ushort8v*)&hcat[(size_t)s0 * 512 + 256 + c0];
        const ushort8v h1 = *(const ushort8v*)&hcat[(size_t)s1 * 512 + 256 + c0];
#pragma unroll
        for (int j = 0; j < 8; ++j) acc[j] += us2f(h0[j]) + us2f(h1[j]);
    }
    if (p < p1l) {
        const int s0 = ssort[p];
        const ushort8v h0 = *(const ushort8v*)&hcat[(size_t)s0 * 512 + 256 + c0];
#pragma unroll
        for (int j = 0; j < 8; ++j) acc[j] += us2f(h0[j]);
    }
#pragma unroll
    for (int j = 0; j < 8; ++j) acc[j] += __shfl_xor(acc[j], 32);

    const float inv = (deg > 0) ? 1.0f / (float)deg : 0.f;
    if (slot2 == 0) {
        ushort8v o;
#pragma unroll
        for (int j = 0; j < 8; ++j) o[j] = f2us(acc[j] * inv);
        *(ushort8v*)&hcat[(size_t)v * 512 + c0] = o;
    }
}

// ---------------------------------------------------------------------------
extern "C" void kernel_launch(void* const* d_in, const int* in_sizes, int n_in,
                              void* d_out, int out_size, void* d_ws, size_t ws_size,
                              hipStream_t stream)
{
    const float* x    = (const float*)d_in[0];
    const float* Wg   = (const float*)d_in[1];
    const float* asrc = (const float*)d_in[2];
    const float* adst = (const float*)d_in[3];
    const float* bg   = (const float*)d_in[4];
    const float* Wl1  = (const float*)d_in[8];
    const float* bl1  = (const float*)d_in[9];
    const float* Wr1  = (const float*)d_in[10];
    const int*   src1 = (const int*)d_in[13];
    const int*   dst1 = (const int*)d_in[14];
    const int E1 = in_sizes[13];

    // workspace
    char* w = (char*)d_ws;
    unsigned short* hb   = (unsigned short*)w; w += (size_t)NS * 256 * 2;   // 40.96 MB
    unsigned short* hcat = (unsigned short*)w; w += (size_t)ND * 512 * 2;   // 20.48 MB
    unsigned short* Wgt  = (unsigned short*)w; w += 256 * 256 * 2;
    unsigned short* Wcat = (unsigned short*)w; w += 256 * 512 * 2;
    float* al_s   = (float*)w; w += (size_t)NS * 4;
    float* al_d   = (float*)w; w += (size_t)NS * 4;
    int* cntpair  = (int*)w;   w += (size_t)2 * ND * 4;
    int* ptrv     = (int*)w;   w += (size_t)(ND + 4) * 4;
    int* rank     = (int*)w;   w += (size_t)E1 * 4;
    int* ssort    = (int*)w;   w += (size_t)E1 * 4;

    const dim3 b256(256), b512(512);
    const int nz4 = 2 * ND / 4;   // cntpair in int4s

    prep_misc<<<dim3(512 + (nz4 + 255) / 256), b256, 0, stream>>>(
        Wg, Wl1, Wr1, Wgt, Wcat, cntpair, nz4);

    count_rank<<<dim3((E1 + 255) / 256), b256, 0, stream>>>(
        src1, dst1, cntpair, rank, E1);

    // h = x @ Wg + bg (bf16) with fused pre-bias al_s/al_d; scan fused
    const int nblk0 = NS / 128;
    gemm_mfma<0, true, true><<<dim3(nblk0 + 1), b512, 0, stream>>>(
        x, Wgt, NS, 256, hb, asrc, adst, al_s, al_d, bg, nullptr,
        nblk0, cntpair, ptrv);

    edge_scatter<<<dim3((E1 + 255) / 256), b256, 0, stream>>>(
        src1, dst1, ptrv, rank, cntpair, ssort, E1);

    // fused GAT aggregate + SAGE s>=ND partial sum (psum bf16 in-place)
    gat_sage<<<dim3(ND), dim3(128), 0, stream>>>(hb, al_s, al_d, ssort,
                                                 ptrv, hcat);
    // SAGE finisher: s<ND h1a gathers + divide
    sage_fin<<<dim3(ND / 4), b256, 0, stream>>>(ssort, ptrv, cntpair, hcat);

    // out = normalize([mean|h1a] @ [Wl1;Wr1] + bl1)
    gemm_mfma<1, false, false><<<dim3((ND + 127) / 128), b512, 0, stream>>>(
        hcat, Wcat, ND, 512, nullptr, nullptr, nullptr, nullptr, nullptr,
        bl1, (float*)d_out, 0, nullptr, nullptr);
}